// Round 2
// 202.222 us; speedup vs baseline: 1.0237x; 1.0237x over previous
//
#include <hip/hip_runtime.h>
#include <math.h>

#define NB 2
#define NL 2048
#define NK 32
#define NODE_F 128
#define EDGE_F 128

// output layout (float32 elements)
#define OFF_HV   0
#define OFF_HE   (NB*NL*NODE_F)                 // 524288
#define OFF_EIDX (OFF_HE + NB*NL*NK*EDGE_F)     // 17301504
#define OFF_X    (OFF_EIDX + NB*NL*NK)          // 17432576

typedef __attribute__((ext_vector_type(8))) short v8s;
typedef __attribute__((ext_vector_type(4))) float v4f;

__device__ __forceinline__ short f2bf(float f) {
    unsigned u = __float_as_uint(f);
    unsigned r = u + 0x7fffu + ((u >> 16) & 1u);
    return (short)(r >> 16);
}

#if __has_builtin(__builtin_amdgcn_exp2f)
#define EXP2F(x) __builtin_amdgcn_exp2f(x)
#else
#define EXP2F(x) __expf((x) * 0.6931471805599453f)
#endif

// pack top halves of two f32 bit-patterns (truncating f32->bf16) into one u32
__device__ __forceinline__ unsigned bfpack(float f0, float f1) {
    unsigned u0 = __float_as_uint(f0), u1 = __float_as_uint(f1);
#if __has_builtin(__builtin_amdgcn_perm)
    return __builtin_amdgcn_perm(u1, u0, 0x07060302u);  // {u1.hi16, u0.hi16}
#else
    return (u1 & 0xFFFF0000u) | (u0 >> 16);
#endif
}

// ---------------- helpers ----------------
__device__ __forceinline__ void cross3(const float a[3], const float b[3], float c[3]) {
    c[0] = a[1]*b[2] - a[2]*b[1];
    c[1] = a[2]*b[0] - a[0]*b[2];
    c[2] = a[0]*b[1] - a[1]*b[0];
}
__device__ __forceinline__ float dot3(const float a[3], const float b[3]) {
    return a[0]*b[0] + a[1]*b[1] + a[2]*b[2];
}
__device__ float dihedral_f(const float p0[3], const float p1[3],
                            const float p2[3], const float p3[3]) {
    float u0[3], u1[3], u2[3];
    for (int d = 0; d < 3; d++) {
        u0[d] = p2[d] - p1[d];
        u1[d] = p0[d] - p1[d];
        u2[d] = p3[d] - p2[d];
    }
    float n1[3], n2[3], c12[3];
    cross3(u0, u1, n1);
    cross3(u0, u2, n2);
    cross3(u1, u2, c12);
    float l1 = sqrtf(dot3(n1, n1));
    float l2 = sqrtf(dot3(n2, n2));
    float cosang = dot3(n1, n2) / (l1 * l2);
    float s = dot3(c12, u0);
    float sgn = (s > 0.f) ? 1.f : ((s < 0.f) ? -1.f : 0.f);
    float r = sgn * acosf(cosang);
    return isnan(r) ? 0.f : r;
}

// ---------------- kernel 0: W_edge RBF rows -> bf16 MFMA-fragment order ----------------
__global__ void wconv_kernel(const float* __restrict__ We, short* __restrict__ WTf) {
    int t = blockIdx.x * 256 + threadIdx.x;
    if (t >= 13 * 8 * 64) return;
    int lane = t & 63;
    int nt = (t >> 6) & 7;
    int ch = t >> 9;
    int n = nt * 16 + (lane & 15);
    int kbase = ch * 32 + (lane >> 4) * 8;
    short* dst = WTf + (size_t)t * 8;
#pragma unroll
    for (int j = 0; j < 8; j++) {
        int k = kbase + j;
        float f = (k < 400) ? We[(65 + k) * 128 + n] : 0.f;
        dst[j] = f2bf(f);
    }
}

// ---------------- kernel 1: X5 prep + planar Ca + X passthrough ----------------
__global__ void prep_kernel(const float* __restrict__ X, float* __restrict__ X5,
                            float* __restrict__ Cax, float* __restrict__ Cay,
                            float* __restrict__ Caz, float* __restrict__ out) {
    int row = blockIdx.x * blockDim.x + threadIdx.x;
    if (row >= NB * NL) return;
    float v[12];
#pragma unroll
    for (int t = 0; t < 12; t++) v[t] = X[row * 12 + t];
#pragma unroll
    for (int t = 0; t < 12; t++) out[OFF_X + row * 12 + t] = v[t];
    Cax[row] = v[3]; Cay[row] = v[4]; Caz[row] = v[5];
    float bv[3], cv[3], cr[3];
    for (int d = 0; d < 3; d++) { bv[d] = v[3+d] - v[d]; cv[d] = v[6+d] - v[3+d]; }
    cross3(bv, cv, cr);
    float* x5 = X5 + row * 15;
#pragma unroll
    for (int t = 0; t < 12; t++) x5[t] = v[t];
    for (int d = 0; d < 3; d++)
        x5[12 + d] = -0.58273431f * cr[d] + 0.56802827f * bv[d] - 0.54067466f * cv[d] + v[3+d];
}

// ---------------- kernel 2: KNN v7 — zero LDS, 32 f32 distance registers ----------------
__global__ __launch_bounds__(256) void knn7_kernel(const float* __restrict__ Cax,
                                                   const float* __restrict__ Cay,
                                                   const float* __restrict__ Caz,
                                                   const float* __restrict__ mask,
                                                   int* __restrict__ EidxW,
                                                   float* __restrict__ out) {
    int tid = threadIdx.x;
    int w = tid >> 6, l = tid & 63;
    int row = blockIdx.x * 4 + w;     // 4 rows/block, same batch (NL%4==0)
    int b = row / NL;
    int base = b * NL;
    const float* mrow = mask + base;

    float cx = Cax[row], cy = Cay[row], cz = Caz[row];
    float mi = mrow[row - base];

    float K[32];
    float lmax = 0.0f;
#pragma unroll
    for (int t = 0; t < 32; t++) {
        int j = t * 64 + l;
        float dx = __fsub_rn(cx, Cax[base + j]);
        float dy = __fsub_rn(cy, Cay[base + j]);
        float dz = __fsub_rn(cz, Caz[base + j]);
        float ss = __fadd_rn(__fadd_rn(__fadd_rn(__fmul_rn(dx, dx), __fmul_rn(dy, dy)),
                                       __fmul_rn(dz, dz)), 1e-6f);
        float d = __fmul_rn(__fmul_rn(mi, mrow[j]), __fsqrt_rn(ss));
        K[t] = d;
        lmax = fmaxf(lmax, d);
    }
#pragma unroll
    for (int s = 1; s < 64; s <<= 1) lmax = fmaxf(lmax, __shfl_xor(lmax, s, 64));
#pragma unroll
    for (int t = 0; t < 32; t++) {
        int j = t * 64 + l;
        float m2 = __fmul_rn(mi, mrow[j]);
        K[t] = __fadd_rn(K[t], __fmul_rn(__fmul_rn(2.0f, __fsub_rn(1.0f, m2)), lmax));
    }

    const float INF = __int_as_float(0x7F800000);
    int selj = 0;
#pragma unroll 1
    for (int r = 0; r < NK; r++) {
        float bd = K[0];
        int bt = 0;
#pragma unroll
        for (int t = 1; t < 32; t++) {
            bool c = K[t] < bd;
            bd = c ? K[t] : bd;
            bt = c ? t : bt;
        }
        unsigned long long best =
            (((unsigned long long)__float_as_uint(bd)) << 32) |
            (unsigned)((bt << 6) | l);
#pragma unroll
        for (int s = 1; s < 64; s <<= 1) {
            unsigned long long o = __shfl_xor(best, s, 64);
            best = (o < best) ? o : best;
        }
        int bj = (int)(best & 0xFFFFFFFFu);
        int bjs = __builtin_amdgcn_readfirstlane(bj);
        if (l == r) selj = bj;
        bool me = (l == (bjs & 63));
        int btg = bjs >> 6;
#pragma unroll
        for (int t = 0; t < 32; t++)
            K[t] = (me && t == btg) ? INF : K[t];
    }
    if (l < NK) {
        EidxW[row * NK + l] = selj;
        out[OFF_EIDX + row * NK + l] = (float)selj;
    }
}

// ---------------- kernel 3: node features + LN (one wave per row, shfl-only) ----------------
__global__ __launch_bounds__(256) void node2_kernel(const int* __restrict__ S,
                                                    const float* __restrict__ BB,
                                                    const float* __restrict__ SC,
                                                    const float* __restrict__ Wn,
                                                    const float* __restrict__ bn,
                                                    const float* __restrict__ gn,
                                                    const float* __restrict__ betan,
                                                    float* __restrict__ out) {
    int tid = threadIdx.x;
    int w = tid >> 6, l = tid & 63;
    int row = blockIdx.x * 4 + w;
    int f0 = l, f1 = 64 + l;
    int s = S[row];
    float a0 = bn[f0] + Wn[s * NODE_F + f0];
    float a1 = bn[f1] + Wn[s * NODE_F + f1];
#pragma unroll
    for (int t = 0; t < 6; t++) {
        float x = BB[row * 6 + t];
        a0 += x * Wn[(21 + t) * NODE_F + f0];
        a1 += x * Wn[(21 + t) * NODE_F + f1];
    }
#pragma unroll
    for (int t = 0; t < 8; t++) {
        float x = SC[row * 8 + t];
        a0 += x * Wn[(27 + t) * NODE_F + f0];
        a1 += x * Wn[(27 + t) * NODE_F + f1];
    }
    float sm = a0 + a1;
#pragma unroll
    for (int st = 1; st < 64; st <<= 1) sm += __shfl_xor(sm, st, 64);
    float mean = sm * (1.0f / 128.0f);
    float d0 = a0 - mean, d1 = a1 - mean;
    float q = d0 * d0 + d1 * d1;
#pragma unroll
    for (int st = 1; st < 64; st <<= 1) q += __shfl_xor(q, st, 64);
    float rstd = 1.0f / sqrtf(q * (1.0f / 128.0f) + 1e-5f);
    out[OFF_HV + row * NODE_F + f0] = d0 * rstd * gn[f0] + betan[f0];
    out[OFF_HV + row * NODE_F + f1] = d1 * rstd * gn[f1] + betan[f1];
}

// ---------------- kernel 4: edge5 — 64 edges/wave: 4x B-fragment reuse, 256 edges/block ----------------
__global__ __launch_bounds__(256, 2) void edge5_kernel(const float* __restrict__ X5,
                                                       const int* __restrict__ Eidx,
                                                       const int* __restrict__ chain,
                                                       const float* __restrict__ We,
                                                       const float* __restrict__ be,
                                                       const float* __restrict__ ge,
                                                       const float* __restrict__ betae,
                                                       const short* __restrict__ WTf,
                                                       float* __restrict__ out) {
    __shared__ float sXi[8][15];
    __shared__ float sXj[256][17];   // odd stride: no bank conflicts
    __shared__ int sJ[256];
    __shared__ int sPos[256];
    __shared__ float sEt[256], sPhi[256], sPsi[256];
    __shared__ float sDn[25][256];
    __shared__ float sRow[6][128];

    int tid = threadIdx.x;
    int e0 = blockIdx.x * 256;        // 256 edges per block = 8 source rows
    int b = e0 / (NL * NK);
    int i0 = (e0 / NK) % NL;

    sJ[tid] = Eidx[e0 + tid];
    if (tid < 120) sXi[tid / 15][tid % 15] = X5[(b * NL + i0 + tid / 15) * 15 + (tid % 15)];
    for (int t = tid; t < 6 * 128; t += 256) {
        int rr = t >> 7, n2 = t & 127;
        float v;
        if (rr < 3) v = We[(465 + rr) * 128 + n2];
        else if (rr == 3) v = be[n2];
        else if (rr == 4) v = ge[n2];
        else v = betae[n2];
        sRow[rr][n2] = v;
    }
    __syncthreads();
    for (int t = tid; t < 256 * 15; t += 256) {
        int e = t / 15, c2 = t % 15;
        sXj[e][c2] = X5[(b * NL + sJ[e]) * 15 + c2];
    }
    {
        int e = tid;
        int i = i0 + (e >> 5);
        int j = sJ[e];
        int off = j - i + 32;
        off = off < 0 ? 0 : (off > 64 ? 64 : off);
        sPos[e] = off;
        sEt[e] = (chain[b * NL + j] == chain[b * NL + i]) ? 2.0f : 1.0f;
    }
    __syncthreads();
    for (int t = tid; t < 6400; t += 256) {
        int p = t >> 8, e = t & 255;
        int a = p / 5, c2 = p - a * 5;
        const float* xi = &sXi[e >> 5][a * 3];
        const float* xj = &sXj[e][c2 * 3];
        float dx = xi[0] - xj[0], dy = xi[1] - xj[1], dz = xi[2] - xj[2];
        sDn[p][e] = sqrtf(dx * dx + dy * dy + dz * dz + 1e-6f);
    }
    {
        int e = tid;
        const float* xi = sXi[e >> 5];
        const float* xj = sXj[e];
        sPhi[e] = dihedral_f(&xi[6], &xj[0], &xj[3], &xj[6]);
        sPsi[e] = dihedral_f(&xi[0], &xi[3], &xi[6], &xj[0]);
    }
    __syncthreads();   // only barrier before epilogue

    int lane = tid & 63, w = tid >> 6;
    int c = lane & 15, kq = lane >> 4;
    int p0 = kq >> 1;
    float hf = (float)(kq & 1);
    bool tailInvalid = (p0 == 1);   // ch==12 -> pair 25 (k >= 400)

    v4f acc[4][8];
#pragma unroll
    for (int eg = 0; eg < 4; eg++)
#pragma unroll
        for (int nt = 0; nt < 8; nt++) acc[eg][nt] = (v4f){0.f, 0.f, 0.f, 0.f};

    // rbf = exp2(Ac*(e-muj)^2), Ac = -0.64*log2(e); y_j = fma(Bj, e, t1) + Cj
    const float Ac = -0.92332482616893658f;
#pragma unroll 1
    for (int ch = 0; ch < 13; ch++) {
        // B-fragments FIRST: VMEM latency overlaps the A-generation below
        v8s bfr[8];
        const v8s* gb = (const v8s*)WTf + ((size_t)ch * 512 + lane);
#pragma unroll
        for (int nt = 0; nt < 8; nt++) bfr[nt] = gb[nt * 64];

        int pair = 2 * ch + p0;
        int prow = pair < 25 ? pair : 24;

        union { unsigned u[4]; v8s v; } au[4];
#pragma unroll
        for (int eg = 0; eg < 4; eg++) {
            int eA = w * 64 + eg * 16 + c;
            float ee = __fmaf_rn(hf, -10.666666666666666f, sDn[prow][eA]);
            float t1 = Ac * ee * ee;
#pragma unroll
            for (int jp = 0; jp < 4; jp++) {
                const float mu0 = (float)(2 * jp) * (20.0f / 15.0f);
                const float mu1 = (float)(2 * jp + 1) * (20.0f / 15.0f);
                const float B0 = -2.0f * Ac * mu0, C0 = Ac * mu0 * mu0;
                const float B1 = -2.0f * Ac * mu1, C1 = Ac * mu1 * mu1;
                float r0 = EXP2F(__fmaf_rn(B0, ee, t1) + C0);
                float r1 = EXP2F(__fmaf_rn(B1, ee, t1) + C1);
                au[eg].u[jp] = bfpack(r0, r1);
            }
        }
        if (ch == 12 && tailInvalid) {
#pragma unroll
            for (int eg = 0; eg < 4; eg++) {
                au[eg].u[0] = 0; au[eg].u[1] = 0; au[eg].u[2] = 0; au[eg].u[3] = 0;
            }
        }
#pragma unroll
        for (int eg = 0; eg < 4; eg++)
#pragma unroll
            for (int nt = 0; nt < 8; nt++)
                acc[eg][nt] = __builtin_amdgcn_mfma_f32_16x16x32_bf16(au[eg].v, bfr[nt], acc[eg][nt], 0, 0, 0);
    }

    // epilogue: C/D layout col n = nt*16 + (lane&15), row m = kq*4 + r
#pragma unroll
    for (int eg = 0; eg < 4; eg++) {
#pragma unroll
        for (int r = 0; r < 4; r++) {
            int m = kq * 4 + r;
            int e = w * 64 + eg * 16 + m;
            float ph = sPhi[e], ps = sPsi[e], et = sEt[e];
            int pos = sPos[e];
            float vals[8];
            float s = 0.f, q2 = 0.f;
#pragma unroll
            for (int nt = 0; nt < 8; nt++) {
                int n = nt * 16 + c;
                float v = acc[eg][nt][r] + sRow[3][n] + We[pos * 128 + n]
                        + et * sRow[0][n] + ph * sRow[1][n] + ps * sRow[2][n];
                vals[nt] = v;
                s += v;
                q2 += v * v;
            }
#pragma unroll
            for (int s2 = 1; s2 < 16; s2 <<= 1) {
                s  += __shfl_xor(s,  s2, 64);
                q2 += __shfl_xor(q2, s2, 64);
            }
            float mean = s * (1.0f / 128.0f);
            float var = q2 * (1.0f / 128.0f) - mean * mean;
            float rstd = rsqrtf(var + 1e-5f);
#pragma unroll
            for (int nt = 0; nt < 8; nt++) {
                int n = nt * 16 + c;
                out[OFF_HE + (size_t)(e0 + e) * 128 + n] =
                    (vals[nt] - mean) * rstd * sRow[4][n] + sRow[5][n];
            }
        }
    }
}

// ---------------- launch ----------------
extern "C" void kernel_launch(void* const* d_in, const int* in_sizes, int n_in,
                              void* d_out, int out_size, void* d_ws, size_t ws_size,
                              hipStream_t stream) {
    (void)in_sizes; (void)n_in; (void)out_size; (void)ws_size;
    const float* X    = (const float*)d_in[0];
    const int*   S    = (const int*)d_in[1];
    const float* BB   = (const float*)d_in[2];
    const float* SC   = (const float*)d_in[3];
    const int*   chain= (const int*)d_in[4];
    const float* mask = (const float*)d_in[5];
    const float* Wn   = (const float*)d_in[6];
    const float* bn   = (const float*)d_in[7];
    const float* gn   = (const float*)d_in[8];
    const float* betan= (const float*)d_in[9];
    const float* We   = (const float*)d_in[10];
    const float* be   = (const float*)d_in[11];
    const float* ge   = (const float*)d_in[12];
    const float* betae= (const float*)d_in[13];
    float* out = (float*)d_out;

    char* ws = (char*)d_ws;
    int*   EidxW = (int*)ws;                                  // 524288 B
    float* X5    = (float*)(ws + 524288);                     // 245760 B (ends 770048)
    short* WTf   = (short*)(ws + 770048);                     // 106496 B (ends 876544)
    float* Cax   = (float*)(ws + 876544);                     // 16384 B
    float* Cay   = (float*)(ws + 892928);                     // 16384 B
    float* Caz   = (float*)(ws + 909312);                     // 16384 B (ends 925696)

    hipLaunchKernelGGL(wconv_kernel, dim3(26), dim3(256), 0, stream, We, WTf);
    hipLaunchKernelGGL(prep_kernel, dim3((NB * NL + 255) / 256), dim3(256), 0, stream,
                       X, X5, Cax, Cay, Caz, out);
    hipLaunchKernelGGL(knn7_kernel, dim3(NB * NL / 4), dim3(256), 0, stream,
                       Cax, Cay, Caz, mask, EidxW, out);
    hipLaunchKernelGGL(node2_kernel, dim3(NB * NL / 4), dim3(256), 0, stream,
                       S, BB, SC, Wn, bn, gn, betan, out);
    hipLaunchKernelGGL(edge5_kernel, dim3(NB * NL * NK / 256), dim3(256), 0, stream,
                       X5, EidxW, chain, We, be, ge, betae, WTf, out);
}

// Round 3
// 200.044 us; speedup vs baseline: 1.0348x; 1.0109x over previous
//
#include <hip/hip_runtime.h>
#include <math.h>

#define NB 2
#define NL 2048
#define NK 32
#define NODE_F 128
#define EDGE_F 128

// output layout (float32 elements)
#define OFF_HV   0
#define OFF_HE   (NB*NL*NODE_F)                 // 524288
#define OFF_EIDX (OFF_HE + NB*NL*NK*EDGE_F)     // 17301504
#define OFF_X    (OFF_EIDX + NB*NL*NK)          // 17432576

#define ACH 7        // chunks (K=32) in half A
#define BCH 6        // chunks in half B
#define SAW 232      // sA row stride in shorts (464 B, 16B-aligned, 116 dw -> bank-friendly)

typedef __attribute__((ext_vector_type(8))) short v8s;
typedef __attribute__((ext_vector_type(4))) float v4f;

__device__ __forceinline__ short f2bf(float f) {
    unsigned u = __float_as_uint(f);
    unsigned r = u + 0x7fffu + ((u >> 16) & 1u);
    return (short)(r >> 16);
}

#if __has_builtin(__builtin_amdgcn_exp2f)
#define EXP2F(x) __builtin_amdgcn_exp2f(x)
#else
#define EXP2F(x) __expf((x) * 0.6931471805599453f)
#endif

// pack top halves of two f32 bit-patterns (truncating f32->bf16) into one u32
__device__ __forceinline__ unsigned bfpack(float f0, float f1) {
    unsigned u0 = __float_as_uint(f0), u1 = __float_as_uint(f1);
#if __has_builtin(__builtin_amdgcn_perm)
    return __builtin_amdgcn_perm(u1, u0, 0x07060302u);  // {u1.hi16, u0.hi16}
#else
    return (u1 & 0xFFFF0000u) | (u0 >> 16);
#endif
}

// ---------------- helpers ----------------
__device__ __forceinline__ void cross3(const float a[3], const float b[3], float c[3]) {
    c[0] = a[1]*b[2] - a[2]*b[1];
    c[1] = a[2]*b[0] - a[0]*b[2];
    c[2] = a[0]*b[1] - a[1]*b[0];
}
__device__ __forceinline__ float dot3(const float a[3], const float b[3]) {
    return a[0]*b[0] + a[1]*b[1] + a[2]*b[2];
}
__device__ float dihedral_f(const float p0[3], const float p1[3],
                            const float p2[3], const float p3[3]) {
    float u0[3], u1[3], u2[3];
    for (int d = 0; d < 3; d++) {
        u0[d] = p2[d] - p1[d];
        u1[d] = p0[d] - p1[d];
        u2[d] = p3[d] - p2[d];
    }
    float n1[3], n2[3], c12[3];
    cross3(u0, u1, n1);
    cross3(u0, u2, n2);
    cross3(u1, u2, c12);
    float l1 = sqrtf(dot3(n1, n1));
    float l2 = sqrtf(dot3(n2, n2));
    float cosang = dot3(n1, n2) / (l1 * l2);
    float s = dot3(c12, u0);
    float sgn = (s > 0.f) ? 1.f : ((s < 0.f) ? -1.f : 0.f);
    float r = sgn * acosf(cosang);
    return isnan(r) ? 0.f : r;
}

// ---------------- kernel 0: W_edge RBF rows -> bf16 MFMA-fragment order ----------------
__global__ void wconv_kernel(const float* __restrict__ We, short* __restrict__ WTf) {
    int t = blockIdx.x * 256 + threadIdx.x;
    if (t >= 13 * 8 * 64) return;
    int lane = t & 63;
    int nt = (t >> 6) & 7;
    int ch = t >> 9;
    int n = nt * 16 + (lane & 15);
    int kbase = ch * 32 + (lane >> 4) * 8;
    short* dst = WTf + (size_t)t * 8;
#pragma unroll
    for (int j = 0; j < 8; j++) {
        int k = kbase + j;
        float f = (k < 400) ? We[(65 + k) * 128 + n] : 0.f;
        dst[j] = f2bf(f);
    }
}

// ---------------- kernel 1: X5 prep + planar Ca + X passthrough ----------------
__global__ void prep_kernel(const float* __restrict__ X, float* __restrict__ X5,
                            float* __restrict__ Cax, float* __restrict__ Cay,
                            float* __restrict__ Caz, float* __restrict__ out) {
    int row = blockIdx.x * blockDim.x + threadIdx.x;
    if (row >= NB * NL) return;
    float v[12];
#pragma unroll
    for (int t = 0; t < 12; t++) v[t] = X[row * 12 + t];
#pragma unroll
    for (int t = 0; t < 12; t++) out[OFF_X + row * 12 + t] = v[t];
    Cax[row] = v[3]; Cay[row] = v[4]; Caz[row] = v[5];
    float bv[3], cv[3], cr[3];
    for (int d = 0; d < 3; d++) { bv[d] = v[3+d] - v[d]; cv[d] = v[6+d] - v[3+d]; }
    cross3(bv, cv, cr);
    float* x5 = X5 + row * 15;
#pragma unroll
    for (int t = 0; t < 12; t++) x5[t] = v[t];
    for (int d = 0; d < 3; d++)
        x5[12 + d] = -0.58273431f * cr[d] + 0.56802827f * bv[d] - 0.54067466f * cv[d] + v[3+d];
}

// ---------------- kernel 2: KNN v7 — zero LDS, 32 f32 distance registers ----------------
__global__ __launch_bounds__(256) void knn7_kernel(const float* __restrict__ Cax,
                                                   const float* __restrict__ Cay,
                                                   const float* __restrict__ Caz,
                                                   const float* __restrict__ mask,
                                                   int* __restrict__ EidxW,
                                                   float* __restrict__ out) {
    int tid = threadIdx.x;
    int w = tid >> 6, l = tid & 63;
    int row = blockIdx.x * 4 + w;     // 4 rows/block, same batch (NL%4==0)
    int b = row / NL;
    int base = b * NL;
    const float* mrow = mask + base;

    float cx = Cax[row], cy = Cay[row], cz = Caz[row];
    float mi = mrow[row - base];

    float K[32];
    float lmax = 0.0f;
#pragma unroll
    for (int t = 0; t < 32; t++) {
        int j = t * 64 + l;
        float dx = __fsub_rn(cx, Cax[base + j]);
        float dy = __fsub_rn(cy, Cay[base + j]);
        float dz = __fsub_rn(cz, Caz[base + j]);
        float ss = __fadd_rn(__fadd_rn(__fadd_rn(__fmul_rn(dx, dx), __fmul_rn(dy, dy)),
                                       __fmul_rn(dz, dz)), 1e-6f);
        float d = __fmul_rn(__fmul_rn(mi, mrow[j]), __fsqrt_rn(ss));
        K[t] = d;
        lmax = fmaxf(lmax, d);
    }
#pragma unroll
    for (int s = 1; s < 64; s <<= 1) lmax = fmaxf(lmax, __shfl_xor(lmax, s, 64));
#pragma unroll
    for (int t = 0; t < 32; t++) {
        int j = t * 64 + l;
        float m2 = __fmul_rn(mi, mrow[j]);
        K[t] = __fadd_rn(K[t], __fmul_rn(__fmul_rn(2.0f, __fsub_rn(1.0f, m2)), lmax));
    }

    const float INF = __int_as_float(0x7F800000);
    int selj = 0;
#pragma unroll 1
    for (int r = 0; r < NK; r++) {
        float bd = K[0];
        int bt = 0;
#pragma unroll
        for (int t = 1; t < 32; t++) {
            bool c = K[t] < bd;
            bd = c ? K[t] : bd;
            bt = c ? t : bt;
        }
        unsigned long long best =
            (((unsigned long long)__float_as_uint(bd)) << 32) |
            (unsigned)((bt << 6) | l);
#pragma unroll
        for (int s = 1; s < 64; s <<= 1) {
            unsigned long long o = __shfl_xor(best, s, 64);
            best = (o < best) ? o : best;
        }
        int bj = (int)(best & 0xFFFFFFFFu);
        int bjs = __builtin_amdgcn_readfirstlane(bj);
        if (l == r) selj = bj;
        bool me = (l == (bjs & 63));
        int btg = bjs >> 6;
#pragma unroll
        for (int t = 0; t < 32; t++)
            K[t] = (me && t == btg) ? INF : K[t];
    }
    if (l < NK) {
        EidxW[row * NK + l] = selj;
        out[OFF_EIDX + row * NK + l] = (float)selj;
    }
}

// ---------------- kernel 3: node features + LN (one wave per row, shfl-only) ----------------
__global__ __launch_bounds__(256) void node2_kernel(const int* __restrict__ S,
                                                    const float* __restrict__ BB,
                                                    const float* __restrict__ SC,
                                                    const float* __restrict__ Wn,
                                                    const float* __restrict__ bn,
                                                    const float* __restrict__ gn,
                                                    const float* __restrict__ betan,
                                                    float* __restrict__ out) {
    int tid = threadIdx.x;
    int w = tid >> 6, l = tid & 63;
    int row = blockIdx.x * 4 + w;
    int f0 = l, f1 = 64 + l;
    int s = S[row];
    float a0 = bn[f0] + Wn[s * NODE_F + f0];
    float a1 = bn[f1] + Wn[s * NODE_F + f1];
#pragma unroll
    for (int t = 0; t < 6; t++) {
        float x = BB[row * 6 + t];
        a0 += x * Wn[(21 + t) * NODE_F + f0];
        a1 += x * Wn[(21 + t) * NODE_F + f1];
    }
#pragma unroll
    for (int t = 0; t < 8; t++) {
        float x = SC[row * 8 + t];
        a0 += x * Wn[(27 + t) * NODE_F + f0];
        a1 += x * Wn[(27 + t) * NODE_F + f1];
    }
    float sm = a0 + a1;
#pragma unroll
    for (int st = 1; st < 64; st <<= 1) sm += __shfl_xor(sm, st, 64);
    float mean = sm * (1.0f / 128.0f);
    float d0 = a0 - mean, d1 = a1 - mean;
    float q = d0 * d0 + d1 * d1;
#pragma unroll
    for (int st = 1; st < 64; st <<= 1) q += __shfl_xor(q, st, 64);
    float rstd = 1.0f / sqrtf(q * (1.0f / 128.0f) + 1e-5f);
    out[OFF_HV + row * NODE_F + f0] = d0 * rstd * gn[f0] + betan[f0];
    out[OFF_HV + row * NODE_F + f1] = d1 * rstd * gn[f1] + betan[f1];
}

// ---------------- kernel 4: edge6 — A-matrix staged in LDS, waves split N: 4x B reuse, 32-reg acc ----------------
__global__ __launch_bounds__(256, 4) void edge6_kernel(const float* __restrict__ X5,
                                                       const int* __restrict__ Eidx,
                                                       const int* __restrict__ chain,
                                                       const float* __restrict__ We,
                                                       const float* __restrict__ be,
                                                       const float* __restrict__ ge,
                                                       const float* __restrict__ betae,
                                                       const short* __restrict__ WTf,
                                                       float* __restrict__ out) {
    __shared__ short sA[64 * SAW];        // 29696 B : bf16 A-matrix, one K-half at a time
    __shared__ float sXj[64][17];         // 4352 B  : aliased by sRed in the epilogue
    __shared__ float sXi[2][15];          // 120 B
    __shared__ float sRow[6][128];        // 3072 B
    __shared__ int   sJ[64];              // 256 B
    __shared__ int   sPos[64];            // 256 B
    __shared__ float sEt[64], sPhi[64], sPsi[64];   // 768 B   (total ~38.5 KB -> 4 blocks/CU)

    int tid = threadIdx.x;
    int e0 = blockIdx.x * 64;
    int b = e0 / (NL * NK);
    int i0 = (e0 / NK) % NL;
    int lane = tid & 63, w = tid >> 6;

    // ---- phase 0a: indices + small tables
    if (tid < 64) sJ[tid] = Eidx[e0 + tid];
    if (tid < 30) sXi[tid / 15][tid % 15] = X5[(b * NL + i0 + tid / 15) * 15 + (tid % 15)];
    for (int t = tid; t < 6 * 128; t += 256) {
        int rr = t >> 7, n2 = t & 127;
        float v;
        if (rr < 3) v = We[(465 + rr) * 128 + n2];
        else if (rr == 3) v = be[n2];
        else if (rr == 4) v = ge[n2];
        else v = betae[n2];
        sRow[rr][n2] = v;
    }
    __syncthreads();

    // ---- phase 0b: gather neighbor coords, pos/type
    for (int t = tid; t < 64 * 15; t += 256) {
        int e = t / 15, c2 = t % 15;
        sXj[e][c2] = X5[(b * NL + sJ[e]) * 15 + c2];
    }
    if (tid < 64) {
        int e = tid;
        int i = i0 + (e >> 5);
        int j = sJ[e];
        int off = j - i + 32;
        off = off < 0 ? 0 : (off > 64 ? 64 : off);
        sPos[e] = off;
        sEt[e] = (chain[b * NL + j] == chain[b * NL + i]) ? 2.0f : 1.0f;
    }
    __syncthreads();

    // ---- phase 0c: dihedrals on threads 0..127 (needs sXj)
    if (tid < 128) {
        int e = tid & 63;
        const float* xi = sXi[e >> 5];
        const float* xj = sXj[e];
        if (tid < 64) sPhi[e] = dihedral_f(&xi[6], &xj[0], &xj[3], &xj[6]);
        else          sPsi[e] = dihedral_f(&xi[0], &xi[3], &xi[6], &xj[0]);
    }

    // ---- A-matrix generator for one K-half: all 256 threads.
    // lane covers edge e = w*16 + (lane&15); quarter q = lane>>4 covers octets o = q, q+4, ...
    // octet o -> global k = h*224 + o*8; pair = k>>4 (>=25 -> zero pad); value bf16-packed, b128 write.
    const float Ac = -0.92332482616893658f;   // -log2(e)/1.5625
    int eg_ = w * 16 + (lane & 15);
    int q_ = lane >> 4;
    const float* xiG = sXi[eg_ >> 5];
    const float* xjG = sXj[eg_];
    short* rowp = sA + eg_ * SAW;
    float hfq = (float)(q_ & 1);              // o&1 == q&1 (o = q + 4t)

#define GEN_A(hh, CNT)                                                         \
    {                                                                          \
        _Pragma("unroll")                                                      \
        for (int t = 0; t < (CNT); t++) {                                      \
            int o = q_ + t * 4;                                                \
            int kg = (hh) * 224 + o * 8;                                       \
            int pair = kg >> 4;                                                \
            union { unsigned u[4]; v8s v; } au;                                \
            if (pair >= 25) {                                                  \
                au.u[0] = 0; au.u[1] = 0; au.u[2] = 0; au.u[3] = 0;            \
            } else {                                                           \
                int a = pair / 5, cc = pair - a * 5;                           \
                float dx = xiG[a*3+0] - xjG[cc*3+0];                           \
                float dy = xiG[a*3+1] - xjG[cc*3+1];                           \
                float dz = xiG[a*3+2] - xjG[cc*3+2];                           \
                float d = sqrtf(dx*dx + dy*dy + dz*dz + 1e-6f);                \
                float ee = __fmaf_rn(hfq, -10.666666666666666f, d);            \
                float t1 = Ac * ee * ee;                                       \
                _Pragma("unroll")                                              \
                for (int jp = 0; jp < 4; jp++) {                               \
                    const float mu0 = (float)(2 * jp) * (20.0f / 15.0f);       \
                    const float mu1 = (float)(2 * jp + 1) * (20.0f / 15.0f);   \
                    const float B0 = -2.0f * Ac * mu0, C0 = Ac * mu0 * mu0;    \
                    const float B1 = -2.0f * Ac * mu1, C1 = Ac * mu1 * mu1;    \
                    float r0 = EXP2F(__fmaf_rn(B0, ee, t1) + C0);              \
                    float r1 = EXP2F(__fmaf_rn(B1, ee, t1) + C1);              \
                    au.u[jp] = bfpack(r0, r1);                                 \
                }                                                              \
            }                                                                  \
            *(v8s*)(rowp + o * 8) = au.v;                                      \
        }                                                                      \
    }

    GEN_A(0, ACH)
    __syncthreads();

    // ---- MFMA: waves split N (2 nt tiles each); A from LDS, B from L2 (read once per block)
    int cl = lane & 15, kq = lane >> 4;
    int ntA = 2 * w, ntB = ntA + 1;
    const char* sAc = (const char*)sA;
    int abase0 = cl * (SAW * 2) + kq * 16;

    v4f acc[4][2];
#pragma unroll
    for (int eg = 0; eg < 4; eg++) { acc[eg][0] = (v4f){0.f,0.f,0.f,0.f}; acc[eg][1] = (v4f){0.f,0.f,0.f,0.f}; }

#define MMA_HALF(CHBASE, CNT)                                                  \
    {                                                                          \
        _Pragma("unroll 2")                                                    \
        for (int chl = 0; chl < (CNT); chl++) {                                \
            const v8s* gb = (const v8s*)WTf + ((size_t)((CHBASE) + chl) * 512 + lane); \
            v8s b0 = gb[ntA * 64];                                             \
            v8s b1 = gb[ntB * 64];                                             \
            int ab = abase0 + chl * 64;                                        \
            v8s a0 = *(const v8s*)(sAc + ab);                                  \
            v8s a1 = *(const v8s*)(sAc + ab + 16 * (SAW * 2));                 \
            v8s a2 = *(const v8s*)(sAc + ab + 32 * (SAW * 2));                 \
            v8s a3 = *(const v8s*)(sAc + ab + 48 * (SAW * 2));                 \
            acc[0][0] = __builtin_amdgcn_mfma_f32_16x16x32_bf16(a0, b0, acc[0][0], 0, 0, 0); \
            acc[0][1] = __builtin_amdgcn_mfma_f32_16x16x32_bf16(a0, b1, acc[0][1], 0, 0, 0); \
            acc[1][0] = __builtin_amdgcn_mfma_f32_16x16x32_bf16(a1, b0, acc[1][0], 0, 0, 0); \
            acc[1][1] = __builtin_amdgcn_mfma_f32_16x16x32_bf16(a1, b1, acc[1][1], 0, 0, 0); \
            acc[2][0] = __builtin_amdgcn_mfma_f32_16x16x32_bf16(a2, b0, acc[2][0], 0, 0, 0); \
            acc[2][1] = __builtin_amdgcn_mfma_f32_16x16x32_bf16(a2, b1, acc[2][1], 0, 0, 0); \
            acc[3][0] = __builtin_amdgcn_mfma_f32_16x16x32_bf16(a3, b0, acc[3][0], 0, 0, 0); \
            acc[3][1] = __builtin_amdgcn_mfma_f32_16x16x32_bf16(a3, b1, acc[3][1], 0, 0, 0); \
        }                                                                      \
    }

    MMA_HALF(0, ACH)
    __syncthreads();          // all waves done reading sA half A
    GEN_A(1, BCH)
    __syncthreads();
    MMA_HALF(ACH, BCH)

    // ---- epilogue: vals + cross-wave LN (sRed aliases dead sXj)
    float2* sRed = (float2*)&sXj[0][0];   // [64 edges][4 waves]
    int nA = ntA * 16 + cl, nB = nA + 16;
    float r0A = sRow[0][nA], r1A = sRow[1][nA], r2A = sRow[2][nA];
    float r3A = sRow[3][nA], r4A = sRow[4][nA], r5A = sRow[5][nA];
    float r0B = sRow[0][nB], r1B = sRow[1][nB], r2B = sRow[2][nB];
    float r3B = sRow[3][nB], r4B = sRow[4][nB], r5B = sRow[5][nB];

#pragma unroll
    for (int eg = 0; eg < 4; eg++) {
#pragma unroll
        for (int r = 0; r < 4; r++) {
            int e = eg * 16 + kq * 4 + r;
            float ph = sPhi[e], ps = sPsi[e], et = sEt[e];
            int pos = sPos[e];
            float v0 = acc[eg][0][r] + r3A + We[pos * 128 + nA] + et * r0A + ph * r1A + ps * r2A;
            float v1 = acc[eg][1][r] + r3B + We[pos * 128 + nB] + et * r0B + ph * r1B + ps * r2B;
            acc[eg][0][r] = v0; acc[eg][1][r] = v1;
            float s = v0 + v1, q2 = v0 * v0 + v1 * v1;
#pragma unroll
            for (int s2 = 1; s2 < 16; s2 <<= 1) {
                s  += __shfl_xor(s,  s2, 64);
                q2 += __shfl_xor(q2, s2, 64);
            }
            if (cl == 0) sRed[e * 4 + w] = make_float2(s, q2);
        }
    }
    __syncthreads();

#pragma unroll
    for (int eg = 0; eg < 4; eg++) {
#pragma unroll
        for (int r = 0; r < 4; r++) {
            int e = eg * 16 + kq * 4 + r;
            float4 pa = *(const float4*)&sRed[e * 4];
            float4 pb = *(const float4*)&sRed[e * 4 + 2];
            float s  = pa.x + pa.z + pb.x + pb.z;
            float q2 = pa.y + pa.w + pb.y + pb.w;
            float mean = s * (1.0f / 128.0f);
            float var = q2 * (1.0f / 128.0f) - mean * mean;
            float rstd = rsqrtf(var + 1e-5f);
            size_t base = OFF_HE + (size_t)(e0 + e) * 128;
            out[base + nA] = (acc[eg][0][r] - mean) * rstd * r4A + r5A;
            out[base + nB] = (acc[eg][1][r] - mean) * rstd * r4B + r5B;
        }
    }
}

// ---------------- launch ----------------
extern "C" void kernel_launch(void* const* d_in, const int* in_sizes, int n_in,
                              void* d_out, int out_size, void* d_ws, size_t ws_size,
                              hipStream_t stream) {
    (void)in_sizes; (void)n_in; (void)out_size; (void)ws_size;
    const float* X    = (const float*)d_in[0];
    const int*   S    = (const int*)d_in[1];
    const float* BB   = (const float*)d_in[2];
    const float* SC   = (const float*)d_in[3];
    const int*   chain= (const int*)d_in[4];
    const float* mask = (const float*)d_in[5];
    const float* Wn   = (const float*)d_in[6];
    const float* bn   = (const float*)d_in[7];
    const float* gn   = (const float*)d_in[8];
    const float* betan= (const float*)d_in[9];
    const float* We   = (const float*)d_in[10];
    const float* be   = (const float*)d_in[11];
    const float* ge   = (const float*)d_in[12];
    const float* betae= (const float*)d_in[13];
    float* out = (float*)d_out;

    char* ws = (char*)d_ws;
    int*   EidxW = (int*)ws;                                  // 524288 B
    float* X5    = (float*)(ws + 524288);                     // 245760 B (ends 770048)
    short* WTf   = (short*)(ws + 770048);                     // 106496 B (ends 876544)
    float* Cax   = (float*)(ws + 876544);                     // 16384 B
    float* Cay   = (float*)(ws + 892928);                     // 16384 B
    float* Caz   = (float*)(ws + 909312);                     // 16384 B (ends 925696)

    hipLaunchKernelGGL(wconv_kernel, dim3(26), dim3(256), 0, stream, We, WTf);
    hipLaunchKernelGGL(prep_kernel, dim3((NB * NL + 255) / 256), dim3(256), 0, stream,
                       X, X5, Cax, Cay, Caz, out);
    hipLaunchKernelGGL(knn7_kernel, dim3(NB * NL / 4), dim3(256), 0, stream,
                       Cax, Cay, Caz, mask, EidxW, out);
    hipLaunchKernelGGL(node2_kernel, dim3(NB * NL / 4), dim3(256), 0, stream,
                       S, BB, SC, Wn, bn, gn, betan, out);
    hipLaunchKernelGGL(edge6_kernel, dim3(NB * NL * NK / 64), dim3(256), 0, stream,
                       X5, EidxW, chain, We, be, ge, betae, WTf, out);
}

// Round 4
// 198.807 us; speedup vs baseline: 1.0413x; 1.0062x over previous
//
#include <hip/hip_runtime.h>
#include <math.h>

#define NB 2
#define NL 2048
#define NK 32
#define NODE_F 128
#define EDGE_F 128

// output layout (float32 elements)
#define OFF_HV   0
#define OFF_HE   (NB*NL*NODE_F)                 // 524288
#define OFF_EIDX (OFF_HE + NB*NL*NK*EDGE_F)     // 17301504
#define OFF_X    (OFF_EIDX + NB*NL*NK)          // 17432576

#define ACH 7        // chunks (K=32) in half A
#define BCH 6        // chunks in half B
#define SAW 232      // sA row stride in shorts (464 B, 16B-aligned, bank-friendly)

typedef __attribute__((ext_vector_type(8))) short v8s;
typedef __attribute__((ext_vector_type(4))) float v4f;

__device__ __forceinline__ short f2bf(float f) {
    unsigned u = __float_as_uint(f);
    unsigned r = u + 0x7fffu + ((u >> 16) & 1u);
    return (short)(r >> 16);
}

#if __has_builtin(__builtin_amdgcn_exp2f)
#define EXP2F(x) __builtin_amdgcn_exp2f(x)
#else
#define EXP2F(x) __expf((x) * 0.6931471805599453f)
#endif

// pack top halves of two f32 bit-patterns (truncating f32->bf16) into one u32
__device__ __forceinline__ unsigned bfpack(float f0, float f1) {
    unsigned u0 = __float_as_uint(f0), u1 = __float_as_uint(f1);
#if __has_builtin(__builtin_amdgcn_perm)
    return __builtin_amdgcn_perm(u1, u0, 0x07060302u);  // {u1.hi16, u0.hi16}
#else
    return (u1 & 0xFFFF0000u) | (u0 >> 16);
#endif
}

// ---------------- helpers ----------------
__device__ __forceinline__ void cross3(const float a[3], const float b[3], float c[3]) {
    c[0] = a[1]*b[2] - a[2]*b[1];
    c[1] = a[2]*b[0] - a[0]*b[2];
    c[2] = a[0]*b[1] - a[1]*b[0];
}
__device__ __forceinline__ float dot3(const float a[3], const float b[3]) {
    return a[0]*b[0] + a[1]*b[1] + a[2]*b[2];
}
__device__ float dihedral_f(const float p0[3], const float p1[3],
                            const float p2[3], const float p3[3]) {
    float u0[3], u1[3], u2[3];
    for (int d = 0; d < 3; d++) {
        u0[d] = p2[d] - p1[d];
        u1[d] = p0[d] - p1[d];
        u2[d] = p3[d] - p2[d];
    }
    float n1[3], n2[3], c12[3];
    cross3(u0, u1, n1);
    cross3(u0, u2, n2);
    cross3(u1, u2, c12);
    float l1 = sqrtf(dot3(n1, n1));
    float l2 = sqrtf(dot3(n2, n2));
    float cosang = dot3(n1, n2) / (l1 * l2);
    float s = dot3(c12, u0);
    float sgn = (s > 0.f) ? 1.f : ((s < 0.f) ? -1.f : 0.f);
    float r = sgn * acosf(cosang);
    return isnan(r) ? 0.f : r;
}

// ---------------- kernel 0: W_edge rows -> bf16 MFMA-fragment order ----------------
// k<400: RBF rows We[65+k]. k=400..402: We[465..467] (et/phi/psi rows). k=403: be. else 0.
__global__ void wconv_kernel(const float* __restrict__ We, const float* __restrict__ be,
                             short* __restrict__ WTf) {
    int t = blockIdx.x * 256 + threadIdx.x;
    if (t >= 13 * 8 * 64) return;
    int lane = t & 63;
    int nt = (t >> 6) & 7;
    int ch = t >> 9;
    int n = nt * 16 + (lane & 15);
    int kbase = ch * 32 + (lane >> 4) * 8;
    short* dst = WTf + (size_t)t * 8;
#pragma unroll
    for (int j = 0; j < 8; j++) {
        int k = kbase + j;
        float f;
        if (k < 403) f = We[(65 + k) * 128 + n];       // rows 465..467 are (65+400..402)
        else if (k == 403) f = be[n];
        else f = 0.f;
        dst[j] = f2bf(f);
    }
}

// ---------------- kernel 1: X5 prep + planar Ca + X passthrough ----------------
__global__ void prep_kernel(const float* __restrict__ X, float* __restrict__ X5,
                            float* __restrict__ Cax, float* __restrict__ Cay,
                            float* __restrict__ Caz, float* __restrict__ out) {
    int row = blockIdx.x * blockDim.x + threadIdx.x;
    if (row >= NB * NL) return;
    float v[12];
#pragma unroll
    for (int t = 0; t < 12; t++) v[t] = X[row * 12 + t];
#pragma unroll
    for (int t = 0; t < 12; t++) out[OFF_X + row * 12 + t] = v[t];
    Cax[row] = v[3]; Cay[row] = v[4]; Caz[row] = v[5];
    float bv[3], cv[3], cr[3];
    for (int d = 0; d < 3; d++) { bv[d] = v[3+d] - v[d]; cv[d] = v[6+d] - v[3+d]; }
    cross3(bv, cv, cr);
    float* x5 = X5 + row * 15;
#pragma unroll
    for (int t = 0; t < 12; t++) x5[t] = v[t];
    for (int d = 0; d < 3; d++)
        x5[12 + d] = -0.58273431f * cr[d] + 0.56802827f * bv[d] - 0.54067466f * cv[d] + v[3+d];
}

// ---------------- kernel 2: KNN v8 — u64 keys, incremental quarter-mins ----------------
// key[t] = (f32bits(adjusted d) << 32) | j  ; min over keys == (value, index) lexicographic,
// identical tie semantics to the previous (passing) tournament version.
#define KNN_QMIN(Q) {                                                                  \
    unsigned long long a_ = key[(Q)*8+0] < key[(Q)*8+1] ? key[(Q)*8+0] : key[(Q)*8+1]; \
    unsigned long long b_ = key[(Q)*8+2] < key[(Q)*8+3] ? key[(Q)*8+2] : key[(Q)*8+3]; \
    unsigned long long c_ = key[(Q)*8+4] < key[(Q)*8+5] ? key[(Q)*8+4] : key[(Q)*8+5]; \
    unsigned long long d_ = key[(Q)*8+6] < key[(Q)*8+7] ? key[(Q)*8+6] : key[(Q)*8+7]; \
    a_ = a_ < b_ ? a_ : b_; c_ = c_ < d_ ? c_ : d_;                                    \
    qm[(Q)] = a_ < c_ ? a_ : c_; }

#define KNN_STEP(Q) {                                                                  \
    _Pragma("unroll")                                                                  \
    for (int i_ = 0; i_ < 8; i_++)                                                     \
        key[(Q)*8+i_] = (me && tstar == (Q)*8+i_) ? ~0ull : key[(Q)*8+i_];             \
    KNN_QMIN(Q) }

__global__ __launch_bounds__(256) void knn8_kernel(const float* __restrict__ Cax,
                                                   const float* __restrict__ Cay,
                                                   const float* __restrict__ Caz,
                                                   const float* __restrict__ mask,
                                                   int* __restrict__ EidxW,
                                                   float* __restrict__ out) {
    int tid = threadIdx.x;
    int w = tid >> 6, l = tid & 63;
    int row = blockIdx.x * 4 + w;     // 4 rows/block, same batch (NL%4==0)
    int b = row / NL;
    int base = b * NL;
    const float* mrow = mask + base;

    float cx = Cax[row], cy = Cay[row], cz = Caz[row];
    float mi = mrow[row - base];

    float K[32];
    float lmax = 0.0f;
#pragma unroll
    for (int t = 0; t < 32; t++) {
        int j = t * 64 + l;
        float dx = __fsub_rn(cx, Cax[base + j]);
        float dy = __fsub_rn(cy, Cay[base + j]);
        float dz = __fsub_rn(cz, Caz[base + j]);
        float ss = __fadd_rn(__fadd_rn(__fadd_rn(__fmul_rn(dx, dx), __fmul_rn(dy, dy)),
                                       __fmul_rn(dz, dz)), 1e-6f);
        float d = __fmul_rn(__fmul_rn(mi, mrow[j]), __fsqrt_rn(ss));
        K[t] = d;
        lmax = fmaxf(lmax, d);
    }
#pragma unroll
    for (int s = 1; s < 64; s <<= 1) lmax = fmaxf(lmax, __shfl_xor(lmax, s, 64));
#pragma unroll
    for (int t = 0; t < 32; t++) {
        int j = t * 64 + l;
        float m2 = __fmul_rn(mi, mrow[j]);
        K[t] = __fadd_rn(K[t], __fmul_rn(__fmul_rn(2.0f, __fsub_rn(1.0f, m2)), lmax));
    }

    unsigned long long key[32];
#pragma unroll
    for (int t = 0; t < 32; t++)
        key[t] = (((unsigned long long)__float_as_uint(K[t])) << 32) | (unsigned)(t * 64 + l);

    unsigned long long qm[4];
    KNN_QMIN(0) KNN_QMIN(1) KNN_QMIN(2) KNN_QMIN(3)

    int selj = 0;
#pragma unroll 1
    for (int r = 0; r < NK; r++) {
        unsigned long long m01 = qm[0] < qm[1] ? qm[0] : qm[1];
        unsigned long long m23 = qm[2] < qm[3] ? qm[2] : qm[3];
        unsigned long long g = m01 < m23 ? m01 : m23;
#pragma unroll
        for (int s = 1; s < 64; s <<= 1) {
            unsigned long long o = __shfl_xor(g, s, 64);
            g = (o < g) ? o : g;
        }
        unsigned j = (unsigned)g;              // j = t*64 + l of the global min
        if (l == r) selj = (int)j;
        bool me = ((j & 63u) == (unsigned)l);
        int tstar = __builtin_amdgcn_readfirstlane((int)(j >> 6));
        switch (tstar >> 3) {
            case 0: KNN_STEP(0) break;
            case 1: KNN_STEP(1) break;
            case 2: KNN_STEP(2) break;
            default: KNN_STEP(3) break;
        }
    }
    if (l < NK) {
        EidxW[row * NK + l] = selj;
        out[OFF_EIDX + row * NK + l] = (float)selj;
    }
}

// ---------------- kernel 3: node features + LN (one wave per row, shfl-only) ----------------
__global__ __launch_bounds__(256) void node2_kernel(const int* __restrict__ S,
                                                    const float* __restrict__ BB,
                                                    const float* __restrict__ SC,
                                                    const float* __restrict__ Wn,
                                                    const float* __restrict__ bn,
                                                    const float* __restrict__ gn,
                                                    const float* __restrict__ betan,
                                                    float* __restrict__ out) {
    int tid = threadIdx.x;
    int w = tid >> 6, l = tid & 63;
    int row = blockIdx.x * 4 + w;
    int f0 = l, f1 = 64 + l;
    int s = S[row];
    float a0 = bn[f0] + Wn[s * NODE_F + f0];
    float a1 = bn[f1] + Wn[s * NODE_F + f1];
#pragma unroll
    for (int t = 0; t < 6; t++) {
        float x = BB[row * 6 + t];
        a0 += x * Wn[(21 + t) * NODE_F + f0];
        a1 += x * Wn[(21 + t) * NODE_F + f1];
    }
#pragma unroll
    for (int t = 0; t < 8; t++) {
        float x = SC[row * 8 + t];
        a0 += x * Wn[(27 + t) * NODE_F + f0];
        a1 += x * Wn[(27 + t) * NODE_F + f1];
    }
    float sm = a0 + a1;
#pragma unroll
    for (int st = 1; st < 64; st <<= 1) sm += __shfl_xor(sm, st, 64);
    float mean = sm * (1.0f / 128.0f);
    float d0 = a0 - mean, d1 = a1 - mean;
    float q = d0 * d0 + d1 * d1;
#pragma unroll
    for (int st = 1; st < 64; st <<= 1) q += __shfl_xor(q, st, 64);
    float rstd = 1.0f / sqrtf(q * (1.0f / 128.0f) + 1e-5f);
    out[OFF_HV + row * NODE_F + f0] = d0 * rstd * gn[f0] + betan[f0];
    out[OFF_HV + row * NODE_F + f1] = d1 * rstd * gn[f1] + betan[f1];
}

// ---------------- kernel 4: edge7 — A in LDS, affine terms folded into K-slots 400..403 ----------------
__global__ __launch_bounds__(256, 4) void edge7_kernel(const float* __restrict__ X5,
                                                       const int* __restrict__ Eidx,
                                                       const int* __restrict__ chain,
                                                       const float* __restrict__ We,
                                                       const float* __restrict__ ge,
                                                       const float* __restrict__ betae,
                                                       const short* __restrict__ WTf,
                                                       float* __restrict__ out) {
    __shared__ short sA[64 * SAW];        // 29696 B : bf16 A-matrix, one K-half at a time
    __shared__ float sXj[64][17];         // 4352 B  : aliased by sRed in the epilogue
    __shared__ float sXi[2][15];          // 120 B
    __shared__ float sRow[2][128];        // 1024 B : ge, betae
    __shared__ int   sJ[64];              // 256 B
    __shared__ int   sPos[64];            // 256 B
    __shared__ float sEt[64], sPhi[64], sPsi[64];   // 768 B   (total ~36.5 KB -> 4 blocks/CU)

    int tid = threadIdx.x;
    int e0 = blockIdx.x * 64;
    int b = e0 / (NL * NK);
    int i0 = (e0 / NK) % NL;
    int lane = tid & 63, w = tid >> 6;

    // ---- phase 0a: indices + small tables
    if (tid < 64) sJ[tid] = Eidx[e0 + tid];
    if (tid < 30) sXi[tid / 15][tid % 15] = X5[(b * NL + i0 + tid / 15) * 15 + (tid % 15)];
    if (tid >= 128 && tid < 128 + 128) {
        int n2 = tid - 128;
        sRow[0][n2] = ge[n2];
        sRow[1][n2] = betae[n2];
    }
    __syncthreads();

    // ---- phase 0b: gather neighbor coords, pos/type
    for (int t = tid; t < 64 * 15; t += 256) {
        int e = t / 15, c2 = t % 15;
        sXj[e][c2] = X5[(b * NL + sJ[e]) * 15 + c2];
    }
    if (tid < 64) {
        int e = tid;
        int i = i0 + (e >> 5);
        int j = sJ[e];
        int off = j - i + 32;
        off = off < 0 ? 0 : (off > 64 ? 64 : off);
        sPos[e] = off;
        sEt[e] = (chain[b * NL + j] == chain[b * NL + i]) ? 2.0f : 1.0f;
    }
    __syncthreads();

    // ---- phase 0c: dihedrals on threads 0..127 (needs sXj); done before first barrier after GEN_A(0)
    if (tid < 128) {
        int e = tid & 63;
        const float* xi = sXi[e >> 5];
        const float* xj = sXj[e];
        if (tid < 64) sPhi[e] = dihedral_f(&xi[6], &xj[0], &xj[3], &xj[6]);
        else          sPsi[e] = dihedral_f(&xi[0], &xi[3], &xi[6], &xj[0]);
    }

    // ---- A-matrix generator for one K-half: all 256 threads.
    // octet o -> global k = h*224 + o*8; pair = k>>4. Special slot kg==400 carries (et,phi,psi,1).
    const float Ac = -0.92332482616893658f;   // -log2(e)/1.5625
    int eg_ = w * 16 + (lane & 15);
    int q_ = lane >> 4;
    const float* xiG = sXi[eg_ >> 5];
    const float* xjG = sXj[eg_];
    short* rowp = sA + eg_ * SAW;
    float hfq = (float)(q_ & 1);              // o&1 == q&1 (o = q + 4t)

#define GEN_A(hh, CNT)                                                         \
    {                                                                          \
        _Pragma("unroll")                                                      \
        for (int t = 0; t < (CNT); t++) {                                      \
            int o = q_ + t * 4;                                                \
            int kg = (hh) * 224 + o * 8;                                       \
            int pair = kg >> 4;                                                \
            union { unsigned u[4]; v8s v; } au;                                \
            if (pair >= 25) {                                                  \
                if ((hh) == 1 && o == 22) {   /* kg==400: affine slots */      \
                    au.u[0] = bfpack(sEt[eg_], sPhi[eg_]);                     \
                    au.u[1] = bfpack(sPsi[eg_], 1.0f);                         \
                    au.u[2] = 0; au.u[3] = 0;                                  \
                } else {                                                       \
                    au.u[0] = 0; au.u[1] = 0; au.u[2] = 0; au.u[3] = 0;        \
                }                                                              \
            } else {                                                           \
                int a = pair / 5, cc = pair - a * 5;                           \
                float dx = xiG[a*3+0] - xjG[cc*3+0];                           \
                float dy = xiG[a*3+1] - xjG[cc*3+1];                           \
                float dz = xiG[a*3+2] - xjG[cc*3+2];                           \
                float d = sqrtf(dx*dx + dy*dy + dz*dz + 1e-6f);                \
                float ee = __fmaf_rn(hfq, -10.666666666666666f, d);            \
                float t1 = Ac * ee * ee;                                       \
                _Pragma("unroll")                                              \
                for (int jp = 0; jp < 4; jp++) {                               \
                    const float mu0 = (float)(2 * jp) * (20.0f / 15.0f);       \
                    const float mu1 = (float)(2 * jp + 1) * (20.0f / 15.0f);   \
                    const float B0 = -2.0f * Ac * mu0, C0 = Ac * mu0 * mu0;    \
                    const float B1 = -2.0f * Ac * mu1, C1 = Ac * mu1 * mu1;    \
                    float r0 = EXP2F(__fmaf_rn(B0, ee, t1) + C0);              \
                    float r1 = EXP2F(__fmaf_rn(B1, ee, t1) + C1);              \
                    au.u[jp] = bfpack(r0, r1);                                 \
                }                                                              \
            }                                                                  \
            *(v8s*)(rowp + o * 8) = au.v;                                      \
        }                                                                      \
    }

    GEN_A(0, ACH)
    __syncthreads();

    // ---- MFMA: waves split N (2 nt tiles each); A from LDS, B from L2 (read once per block)
    int cl = lane & 15, kq = lane >> 4;
    int ntA = 2 * w, ntB = ntA + 1;
    const char* sAc = (const char*)sA;
    int abase0 = cl * (SAW * 2) + kq * 16;

    v4f acc[4][2];
#pragma unroll
    for (int eg = 0; eg < 4; eg++) { acc[eg][0] = (v4f){0.f,0.f,0.f,0.f}; acc[eg][1] = (v4f){0.f,0.f,0.f,0.f}; }

#define MMA_HALF(CHBASE, CNT)                                                  \
    {                                                                          \
        _Pragma("unroll 2")                                                    \
        for (int chl = 0; chl < (CNT); chl++) {                                \
            const v8s* gb = (const v8s*)WTf + ((size_t)((CHBASE) + chl) * 512 + lane); \
            v8s b0 = gb[ntA * 64];                                             \
            v8s b1 = gb[ntB * 64];                                             \
            int ab = abase0 + chl * 64;                                        \
            v8s a0 = *(const v8s*)(sAc + ab);                                  \
            v8s a1 = *(const v8s*)(sAc + ab + 16 * (SAW * 2));                 \
            v8s a2 = *(const v8s*)(sAc + ab + 32 * (SAW * 2));                 \
            v8s a3 = *(const v8s*)(sAc + ab + 48 * (SAW * 2));                 \
            acc[0][0] = __builtin_amdgcn_mfma_f32_16x16x32_bf16(a0, b0, acc[0][0], 0, 0, 0); \
            acc[0][1] = __builtin_amdgcn_mfma_f32_16x16x32_bf16(a0, b1, acc[0][1], 0, 0, 0); \
            acc[1][0] = __builtin_amdgcn_mfma_f32_16x16x32_bf16(a1, b0, acc[1][0], 0, 0, 0); \
            acc[1][1] = __builtin_amdgcn_mfma_f32_16x16x32_bf16(a1, b1, acc[1][1], 0, 0, 0); \
            acc[2][0] = __builtin_amdgcn_mfma_f32_16x16x32_bf16(a2, b0, acc[2][0], 0, 0, 0); \
            acc[2][1] = __builtin_amdgcn_mfma_f32_16x16x32_bf16(a2, b1, acc[2][1], 0, 0, 0); \
            acc[3][0] = __builtin_amdgcn_mfma_f32_16x16x32_bf16(a3, b0, acc[3][0], 0, 0, 0); \
            acc[3][1] = __builtin_amdgcn_mfma_f32_16x16x32_bf16(a3, b1, acc[3][1], 0, 0, 0); \
        }                                                                      \
    }

    MMA_HALF(0, ACH)
    __syncthreads();          // all waves done reading sA half A
    GEN_A(1, BCH)
    __syncthreads();
    MMA_HALF(ACH, BCH)

    // ---- epilogue: vals + cross-wave LN (sRed aliases dead sXj)
    float2* sRed = (float2*)&sXj[0][0];   // [64 edges][4 waves]
    int nA = ntA * 16 + cl, nB = nA + 16;
    float r4A = sRow[0][nA], r5A = sRow[1][nA];
    float r4B = sRow[0][nB], r5B = sRow[1][nB];

#pragma unroll
    for (int eg = 0; eg < 4; eg++) {
#pragma unroll
        for (int r = 0; r < 4; r++) {
            int e = eg * 16 + kq * 4 + r;
            int pos = sPos[e];
            float v0 = acc[eg][0][r] + We[pos * 128 + nA];
            float v1 = acc[eg][1][r] + We[pos * 128 + nB];
            acc[eg][0][r] = v0; acc[eg][1][r] = v1;
            float s = v0 + v1, q2 = v0 * v0 + v1 * v1;
#pragma unroll
            for (int s2 = 1; s2 < 16; s2 <<= 1) {
                s  += __shfl_xor(s,  s2, 64);
                q2 += __shfl_xor(q2, s2, 64);
            }
            if (cl == 0) sRed[e * 4 + w] = make_float2(s, q2);
        }
    }
    __syncthreads();

#pragma unroll
    for (int eg = 0; eg < 4; eg++) {
#pragma unroll
        for (int r = 0; r < 4; r++) {
            int e = eg * 16 + kq * 4 + r;
            float4 pa = *(const float4*)&sRed[e * 4];
            float4 pb = *(const float4*)&sRed[e * 4 + 2];
            float s  = pa.x + pa.z + pb.x + pb.z;
            float q2 = pa.y + pa.w + pb.y + pb.w;
            float mean = s * (1.0f / 128.0f);
            float var = q2 * (1.0f / 128.0f) - mean * mean;
            float rstd = rsqrtf(var + 1e-5f);
            size_t base = OFF_HE + (size_t)(e0 + e) * 128;
            out[base + nA] = (acc[eg][0][r] - mean) * rstd * r4A + r5A;
            out[base + nB] = (acc[eg][1][r] - mean) * rstd * r4B + r5B;
        }
    }
}

// ---------------- launch ----------------
extern "C" void kernel_launch(void* const* d_in, const int* in_sizes, int n_in,
                              void* d_out, int out_size, void* d_ws, size_t ws_size,
                              hipStream_t stream) {
    (void)in_sizes; (void)n_in; (void)out_size; (void)ws_size;
    const float* X    = (const float*)d_in[0];
    const int*   S    = (const int*)d_in[1];
    const float* BB   = (const float*)d_in[2];
    const float* SC   = (const float*)d_in[3];
    const int*   chain= (const int*)d_in[4];
    const float* mask = (const float*)d_in[5];
    const float* Wn   = (const float*)d_in[6];
    const float* bn   = (const float*)d_in[7];
    const float* gn   = (const float*)d_in[8];
    const float* betan= (const float*)d_in[9];
    const float* We   = (const float*)d_in[10];
    const float* be   = (const float*)d_in[11];
    const float* ge   = (const float*)d_in[12];
    const float* betae= (const float*)d_in[13];
    float* out = (float*)d_out;

    char* ws = (char*)d_ws;
    int*   EidxW = (int*)ws;                                  // 524288 B
    float* X5    = (float*)(ws + 524288);                     // 245760 B (ends 770048)
    short* WTf   = (short*)(ws + 770048);                     // 106496 B (ends 876544)
    float* Cax   = (float*)(ws + 876544);                     // 16384 B
    float* Cay   = (float*)(ws + 892928);                     // 16384 B
    float* Caz   = (float*)(ws + 909312);                     // 16384 B (ends 925696)

    hipLaunchKernelGGL(wconv_kernel, dim3(26), dim3(256), 0, stream, We, be, WTf);
    hipLaunchKernelGGL(prep_kernel, dim3((NB * NL + 255) / 256), dim3(256), 0, stream,
                       X, X5, Cax, Cay, Caz, out);
    hipLaunchKernelGGL(knn8_kernel, dim3(NB * NL / 4), dim3(256), 0, stream,
                       Cax, Cay, Caz, mask, EidxW, out);
    hipLaunchKernelGGL(node2_kernel, dim3(NB * NL / 4), dim3(256), 0, stream,
                       S, BB, SC, Wn, bn, gn, betan, out);
    hipLaunchKernelGGL(edge7_kernel, dim3(NB * NL * NK / 64), dim3(256), 0, stream,
                       X5, EidxW, chain, We, ge, betae, WTf, out);
}

// Round 5
// 184.869 us; speedup vs baseline: 1.1198x; 1.0754x over previous
//
#include <hip/hip_runtime.h>
#include <math.h>

#define NB 2
#define NL 2048
#define NK 32
#define NODE_F 128
#define EDGE_F 128

// output layout (float32 elements)
#define OFF_HV   0
#define OFF_HE   (NB*NL*NODE_F)                 // 524288
#define OFF_EIDX (OFF_HE + NB*NL*NK*EDGE_F)     // 17301504
#define OFF_X    (OFF_EIDX + NB*NL*NK)          // 17432576

#define ACH 7        // chunks (K=32) in half A
#define BCH 6        // chunks in half B
#define SAW 232      // sA row stride in shorts (464 B, 16B-aligned, bank-friendly)

typedef __attribute__((ext_vector_type(8))) short v8s;
typedef __attribute__((ext_vector_type(4))) float v4f;

__device__ __forceinline__ short f2bf(float f) {
    unsigned u = __float_as_uint(f);
    unsigned r = u + 0x7fffu + ((u >> 16) & 1u);
    return (short)(r >> 16);
}

#if __has_builtin(__builtin_amdgcn_exp2f)
#define EXP2F(x) __builtin_amdgcn_exp2f(x)
#else
#define EXP2F(x) __expf((x) * 0.6931471805599453f)
#endif

// pack top halves of two f32 bit-patterns (truncating f32->bf16) into one u32
__device__ __forceinline__ unsigned bfpack(float f0, float f1) {
    unsigned u0 = __float_as_uint(f0), u1 = __float_as_uint(f1);
#if __has_builtin(__builtin_amdgcn_perm)
    return __builtin_amdgcn_perm(u1, u0, 0x07060302u);  // {u1.hi16, u0.hi16}
#else
    return (u1 & 0xFFFF0000u) | (u0 >> 16);
#endif
}

// ---------------- DPP wave-min (u64) — no LDS, pure VALU ----------------
template<int CTRL>
__device__ __forceinline__ unsigned long long dpp_min_step(unsigned long long x) {
    unsigned lo = (unsigned)x, hi = (unsigned)(x >> 32);
    unsigned plo = (unsigned)__builtin_amdgcn_update_dpp((int)lo, (int)lo, CTRL, 0xF, 0xF, false);
    unsigned phi = (unsigned)__builtin_amdgcn_update_dpp((int)hi, (int)hi, CTRL, 0xF, 0xF, false);
    unsigned long long p = (((unsigned long long)phi) << 32) | plo;
    return p < x ? p : x;
}
__device__ __forceinline__ unsigned long long wave_min_u64_dpp(unsigned long long x) {
    x = dpp_min_step<0xB1>(x);    // quad_perm [1,0,3,2] : pair min
    x = dpp_min_step<0x4E>(x);    // quad_perm [2,3,0,1] : quad min
    x = dpp_min_step<0x141>(x);   // row_half_mirror     : 8-group min
    x = dpp_min_step<0x140>(x);   // row_mirror          : row(16) min
    x = dpp_min_step<0x142>(x);   // row_bcast15         : rows 1,3 get 2-row min
    x = dpp_min_step<0x143>(x);   // row_bcast31         : lanes 32-63 get global
    return x;                     // lane 63 holds the global min
}

// ---------------- helpers ----------------
__device__ __forceinline__ void cross3(const float a[3], const float b[3], float c[3]) {
    c[0] = a[1]*b[2] - a[2]*b[1];
    c[1] = a[2]*b[0] - a[0]*b[2];
    c[2] = a[0]*b[1] - a[1]*b[0];
}
__device__ __forceinline__ float dot3(const float a[3], const float b[3]) {
    return a[0]*b[0] + a[1]*b[1] + a[2]*b[2];
}
__device__ float dihedral_f(const float p0[3], const float p1[3],
                            const float p2[3], const float p3[3]) {
    float u0[3], u1[3], u2[3];
    for (int d = 0; d < 3; d++) {
        u0[d] = p2[d] - p1[d];
        u1[d] = p0[d] - p1[d];
        u2[d] = p3[d] - p2[d];
    }
    float n1[3], n2[3], c12[3];
    cross3(u0, u1, n1);
    cross3(u0, u2, n2);
    cross3(u1, u2, c12);
    float l1 = sqrtf(dot3(n1, n1));
    float l2 = sqrtf(dot3(n2, n2));
    float cosang = dot3(n1, n2) / (l1 * l2);
    float s = dot3(c12, u0);
    float sgn = (s > 0.f) ? 1.f : ((s < 0.f) ? -1.f : 0.f);
    float r = sgn * acosf(cosang);
    return isnan(r) ? 0.f : r;
}

// ---------------- kernel 0: prep (blocks 0..15) + wconv (blocks 16..41) fused ----------------
// wconv: k<400: RBF rows We[65+k]. k=400..402: We[465..467] (et/phi/psi). k=403: be. else 0.
__global__ void prep_wconv_kernel(const float* __restrict__ X, float* __restrict__ X5,
                                  float* __restrict__ Cax, float* __restrict__ Cay,
                                  float* __restrict__ Caz, float* __restrict__ out,
                                  const float* __restrict__ We, const float* __restrict__ be,
                                  short* __restrict__ WTf) {
    int blk = blockIdx.x;
    if (blk < 16) {
        int row = blk * 256 + threadIdx.x;
        float v[12];
#pragma unroll
        for (int t = 0; t < 12; t++) v[t] = X[row * 12 + t];
#pragma unroll
        for (int t = 0; t < 12; t++) out[OFF_X + row * 12 + t] = v[t];
        Cax[row] = v[3]; Cay[row] = v[4]; Caz[row] = v[5];
        float bv[3], cv[3], cr[3];
        for (int d = 0; d < 3; d++) { bv[d] = v[3+d] - v[d]; cv[d] = v[6+d] - v[3+d]; }
        cross3(bv, cv, cr);
        float* x5 = X5 + row * 15;
#pragma unroll
        for (int t = 0; t < 12; t++) x5[t] = v[t];
        for (int d = 0; d < 3; d++)
            x5[12 + d] = -0.58273431f * cr[d] + 0.56802827f * bv[d] - 0.54067466f * cv[d] + v[3+d];
    } else {
        int t = (blk - 16) * 256 + threadIdx.x;
        if (t >= 13 * 8 * 64) return;
        int lane = t & 63;
        int nt = (t >> 6) & 7;
        int ch = t >> 9;
        int n = nt * 16 + (lane & 15);
        int kbase = ch * 32 + (lane >> 4) * 8;
        short* dst = WTf + (size_t)t * 8;
#pragma unroll
        for (int j = 0; j < 8; j++) {
            int k = kbase + j;
            float f;
            if (k < 403) f = We[(65 + k) * 128 + n];
            else if (k == 403) f = be[n];
            else f = 0.f;
            dst[j] = f2bf(f);
        }
    }
}

// ---------------- kernel 1: node features + KNN v9 (DPP reduce) fused ----------------
#define KNN_QMIN(Q) {                                                                  \
    unsigned long long a_ = key[(Q)*8+0] < key[(Q)*8+1] ? key[(Q)*8+0] : key[(Q)*8+1]; \
    unsigned long long b_ = key[(Q)*8+2] < key[(Q)*8+3] ? key[(Q)*8+2] : key[(Q)*8+3]; \
    unsigned long long c_ = key[(Q)*8+4] < key[(Q)*8+5] ? key[(Q)*8+4] : key[(Q)*8+5]; \
    unsigned long long d_ = key[(Q)*8+6] < key[(Q)*8+7] ? key[(Q)*8+6] : key[(Q)*8+7]; \
    a_ = a_ < b_ ? a_ : b_; c_ = c_ < d_ ? c_ : d_;                                    \
    qm[(Q)] = a_ < c_ ? a_ : c_; }

#define KNN_STEP(Q) {                                                                  \
    _Pragma("unroll")                                                                  \
    for (int i_ = 0; i_ < 8; i_++)                                                     \
        key[(Q)*8+i_] = (me && tstar == (Q)*8+i_) ? ~0ull : key[(Q)*8+i_];             \
    KNN_QMIN(Q) }

__global__ __launch_bounds__(256) void knn_node_kernel(const float* __restrict__ Cax,
                                                       const float* __restrict__ Cay,
                                                       const float* __restrict__ Caz,
                                                       const float* __restrict__ mask,
                                                       const int* __restrict__ S,
                                                       const float* __restrict__ BB,
                                                       const float* __restrict__ SC,
                                                       const float* __restrict__ Wn,
                                                       const float* __restrict__ bn,
                                                       const float* __restrict__ gn,
                                                       const float* __restrict__ betan,
                                                       int* __restrict__ EidxW,
                                                       float* __restrict__ out) {
    int tid = threadIdx.x;
    int w = tid >> 6, l = tid & 63;
    int row = blockIdx.x * 4 + w;     // 4 rows/block, same batch (NL%4==0)

    // ---- node features + LN (memory-latency phase; co-schedules under knn VALU) ----
    {
        int f0 = l, f1 = 64 + l;
        int s = S[row];
        float a0 = bn[f0] + Wn[s * NODE_F + f0];
        float a1 = bn[f1] + Wn[s * NODE_F + f1];
#pragma unroll
        for (int t = 0; t < 6; t++) {
            float x = BB[row * 6 + t];
            a0 += x * Wn[(21 + t) * NODE_F + f0];
            a1 += x * Wn[(21 + t) * NODE_F + f1];
        }
#pragma unroll
        for (int t = 0; t < 8; t++) {
            float x = SC[row * 8 + t];
            a0 += x * Wn[(27 + t) * NODE_F + f0];
            a1 += x * Wn[(27 + t) * NODE_F + f1];
        }
        float sm = a0 + a1;
#pragma unroll
        for (int st = 1; st < 64; st <<= 1) sm += __shfl_xor(sm, st, 64);
        float mean = sm * (1.0f / 128.0f);
        float d0 = a0 - mean, d1 = a1 - mean;
        float q = d0 * d0 + d1 * d1;
#pragma unroll
        for (int st = 1; st < 64; st <<= 1) q += __shfl_xor(q, st, 64);
        float rstd = 1.0f / sqrtf(q * (1.0f / 128.0f) + 1e-5f);
        out[OFF_HV + row * NODE_F + f0] = d0 * rstd * gn[f0] + betan[f0];
        out[OFF_HV + row * NODE_F + f1] = d1 * rstd * gn[f1] + betan[f1];
    }

    // ---- KNN ----
    int b = row / NL;
    int base = b * NL;
    const float* mrow = mask + base;

    float cx = Cax[row], cy = Cay[row], cz = Caz[row];
    float mi = mrow[row - base];

    float K[32];
    float lmax = 0.0f;
#pragma unroll
    for (int t = 0; t < 32; t++) {
        int j = t * 64 + l;
        float dx = __fsub_rn(cx, Cax[base + j]);
        float dy = __fsub_rn(cy, Cay[base + j]);
        float dz = __fsub_rn(cz, Caz[base + j]);
        float ss = __fadd_rn(__fadd_rn(__fadd_rn(__fmul_rn(dx, dx), __fmul_rn(dy, dy)),
                                       __fmul_rn(dz, dz)), 1e-6f);
        float d = __fmul_rn(__fmul_rn(mi, mrow[j]), __fsqrt_rn(ss));
        K[t] = d;
        lmax = fmaxf(lmax, d);
    }
#pragma unroll
    for (int s = 1; s < 64; s <<= 1) lmax = fmaxf(lmax, __shfl_xor(lmax, s, 64));
#pragma unroll
    for (int t = 0; t < 32; t++) {
        int j = t * 64 + l;
        float m2 = __fmul_rn(mi, mrow[j]);
        K[t] = __fadd_rn(K[t], __fmul_rn(__fmul_rn(2.0f, __fsub_rn(1.0f, m2)), lmax));
    }

    unsigned long long key[32];
#pragma unroll
    for (int t = 0; t < 32; t++)
        key[t] = (((unsigned long long)__float_as_uint(K[t])) << 32) | (unsigned)(t * 64 + l);

    unsigned long long qm[4];
    KNN_QMIN(0) KNN_QMIN(1) KNN_QMIN(2) KNN_QMIN(3)

    int selj = 0;
#pragma unroll 1
    for (int r = 0; r < NK; r++) {
        unsigned long long m01 = qm[0] < qm[1] ? qm[0] : qm[1];
        unsigned long long m23 = qm[2] < qm[3] ? qm[2] : qm[3];
        unsigned long long g = m01 < m23 ? m01 : m23;
        g = wave_min_u64_dpp(g);
        unsigned j = (unsigned)__builtin_amdgcn_readlane((int)(unsigned)g, 63);
        if (l == r) selj = (int)j;
        bool me = ((j & 63u) == (unsigned)l);
        int tstar = (int)(j >> 6);
        switch (tstar >> 3) {
            case 0: KNN_STEP(0) break;
            case 1: KNN_STEP(1) break;
            case 2: KNN_STEP(2) break;
            default: KNN_STEP(3) break;
        }
    }
    if (l < NK) {
        EidxW[row * NK + l] = selj;
        out[OFF_EIDX + row * NK + l] = (float)selj;
    }
}

// ---------------- kernel 2: edge7 — A in LDS, affine terms folded into K-slots 400..403 ----------------
__global__ __launch_bounds__(256, 4) void edge7_kernel(const float* __restrict__ X5,
                                                       const int* __restrict__ Eidx,
                                                       const int* __restrict__ chain,
                                                       const float* __restrict__ We,
                                                       const float* __restrict__ ge,
                                                       const float* __restrict__ betae,
                                                       const short* __restrict__ WTf,
                                                       float* __restrict__ out) {
    __shared__ short sA[64 * SAW];        // 29696 B : bf16 A-matrix, one K-half at a time
    __shared__ float sXj[64][17];         // 4352 B  : aliased by sRed in the epilogue
    __shared__ float sXi[2][15];          // 120 B
    __shared__ float sRow[2][128];        // 1024 B : ge, betae
    __shared__ int   sJ[64];              // 256 B
    __shared__ int   sPos[64];            // 256 B
    __shared__ float sEt[64], sPhi[64], sPsi[64];   // 768 B   (total ~36.5 KB -> 4 blocks/CU)

    int tid = threadIdx.x;
    int e0 = blockIdx.x * 64;
    int b = e0 / (NL * NK);
    int i0 = (e0 / NK) % NL;
    int lane = tid & 63, w = tid >> 6;

    // ---- phase 0a: indices + small tables
    if (tid < 64) sJ[tid] = Eidx[e0 + tid];
    if (tid < 30) sXi[tid / 15][tid % 15] = X5[(b * NL + i0 + tid / 15) * 15 + (tid % 15)];
    if (tid >= 128 && tid < 128 + 128) {
        int n2 = tid - 128;
        sRow[0][n2] = ge[n2];
        sRow[1][n2] = betae[n2];
    }
    __syncthreads();

    // ---- phase 0b: gather neighbor coords, pos/type
    for (int t = tid; t < 64 * 15; t += 256) {
        int e = t / 15, c2 = t % 15;
        sXj[e][c2] = X5[(b * NL + sJ[e]) * 15 + c2];
    }
    if (tid < 64) {
        int e = tid;
        int i = i0 + (e >> 5);
        int j = sJ[e];
        int off = j - i + 32;
        off = off < 0 ? 0 : (off > 64 ? 64 : off);
        sPos[e] = off;
        sEt[e] = (chain[b * NL + j] == chain[b * NL + i]) ? 2.0f : 1.0f;
    }
    __syncthreads();

    // ---- phase 0c: dihedrals on threads 0..127 (needs sXj)
    if (tid < 128) {
        int e = tid & 63;
        const float* xi = sXi[e >> 5];
        const float* xj = sXj[e];
        if (tid < 64) sPhi[e] = dihedral_f(&xi[6], &xj[0], &xj[3], &xj[6]);
        else          sPsi[e] = dihedral_f(&xi[0], &xi[3], &xi[6], &xj[0]);
    }

    // ---- A-matrix generator for one K-half: all 256 threads.
    // octet o -> global k = h*224 + o*8; pair = k>>4. Special slot kg==400 carries (et,phi,psi,1).
    const float Ac = -0.92332482616893658f;   // -log2(e)/1.5625
    int eg_ = w * 16 + (lane & 15);
    int q_ = lane >> 4;
    const float* xiG = sXi[eg_ >> 5];
    const float* xjG = sXj[eg_];
    short* rowp = sA + eg_ * SAW;
    float hfq = (float)(q_ & 1);              // o&1 == q&1 (o = q + 4t)

#define GEN_A(hh, CNT)                                                         \
    {                                                                          \
        _Pragma("unroll")                                                      \
        for (int t = 0; t < (CNT); t++) {                                      \
            int o = q_ + t * 4;                                                \
            int kg = (hh) * 224 + o * 8;                                       \
            int pair = kg >> 4;                                                \
            union { unsigned u[4]; v8s v; } au;                                \
            if (pair >= 25) {                                                  \
                if ((hh) == 1 && o == 22) {   /* kg==400: affine slots */      \
                    au.u[0] = bfpack(sEt[eg_], sPhi[eg_]);                     \
                    au.u[1] = bfpack(sPsi[eg_], 1.0f);                         \
                    au.u[2] = 0; au.u[3] = 0;                                  \
                } else {                                                       \
                    au.u[0] = 0; au.u[1] = 0; au.u[2] = 0; au.u[3] = 0;        \
                }                                                              \
            } else {                                                           \
                int a = pair / 5, cc = pair - a * 5;                           \
                float dx = xiG[a*3+0] - xjG[cc*3+0];                           \
                float dy = xiG[a*3+1] - xjG[cc*3+1];                           \
                float dz = xiG[a*3+2] - xjG[cc*3+2];                           \
                float d = sqrtf(dx*dx + dy*dy + dz*dz + 1e-6f);                \
                float ee = __fmaf_rn(hfq, -10.666666666666666f, d);            \
                float t1 = Ac * ee * ee;                                       \
                _Pragma("unroll")                                              \
                for (int jp = 0; jp < 4; jp++) {                               \
                    const float mu0 = (float)(2 * jp) * (20.0f / 15.0f);       \
                    const float mu1 = (float)(2 * jp + 1) * (20.0f / 15.0f);   \
                    const float B0 = -2.0f * Ac * mu0, C0 = Ac * mu0 * mu0;    \
                    const float B1 = -2.0f * Ac * mu1, C1 = Ac * mu1 * mu1;    \
                    float r0 = EXP2F(__fmaf_rn(B0, ee, t1) + C0);              \
                    float r1 = EXP2F(__fmaf_rn(B1, ee, t1) + C1);              \
                    au.u[jp] = bfpack(r0, r1);                                 \
                }                                                              \
            }                                                                  \
            *(v8s*)(rowp + o * 8) = au.v;                                      \
        }                                                                      \
    }

    GEN_A(0, ACH)
    __syncthreads();

    // ---- MFMA: waves split N (2 nt tiles each); A from LDS, B from L2 (read once per block)
    int cl = lane & 15, kq = lane >> 4;
    int ntA = 2 * w, ntB = ntA + 1;
    const char* sAc = (const char*)sA;
    int abase0 = cl * (SAW * 2) + kq * 16;

    v4f acc[4][2];
#pragma unroll
    for (int eg = 0; eg < 4; eg++) { acc[eg][0] = (v4f){0.f,0.f,0.f,0.f}; acc[eg][1] = (v4f){0.f,0.f,0.f,0.f}; }

#define MMA_HALF(CHBASE, CNT)                                                  \
    {                                                                          \
        _Pragma("unroll 2")                                                    \
        for (int chl = 0; chl < (CNT); chl++) {                                \
            const v8s* gb = (const v8s*)WTf + ((size_t)((CHBASE) + chl) * 512 + lane); \
            v8s b0 = gb[ntA * 64];                                             \
            v8s b1 = gb[ntB * 64];                                             \
            int ab = abase0 + chl * 64;                                        \
            v8s a0 = *(const v8s*)(sAc + ab);                                  \
            v8s a1 = *(const v8s*)(sAc + ab + 16 * (SAW * 2));                 \
            v8s a2 = *(const v8s*)(sAc + ab + 32 * (SAW * 2));                 \
            v8s a3 = *(const v8s*)(sAc + ab + 48 * (SAW * 2));                 \
            acc[0][0] = __builtin_amdgcn_mfma_f32_16x16x32_bf16(a0, b0, acc[0][0], 0, 0, 0); \
            acc[0][1] = __builtin_amdgcn_mfma_f32_16x16x32_bf16(a0, b1, acc[0][1], 0, 0, 0); \
            acc[1][0] = __builtin_amdgcn_mfma_f32_16x16x32_bf16(a1, b0, acc[1][0], 0, 0, 0); \
            acc[1][1] = __builtin_amdgcn_mfma_f32_16x16x32_bf16(a1, b1, acc[1][1], 0, 0, 0); \
            acc[2][0] = __builtin_amdgcn_mfma_f32_16x16x32_bf16(a2, b0, acc[2][0], 0, 0, 0); \
            acc[2][1] = __builtin_amdgcn_mfma_f32_16x16x32_bf16(a2, b1, acc[2][1], 0, 0, 0); \
            acc[3][0] = __builtin_amdgcn_mfma_f32_16x16x32_bf16(a3, b0, acc[3][0], 0, 0, 0); \
            acc[3][1] = __builtin_amdgcn_mfma_f32_16x16x32_bf16(a3, b1, acc[3][1], 0, 0, 0); \
        }                                                                      \
    }

    MMA_HALF(0, ACH)
    __syncthreads();          // all waves done reading sA half A
    GEN_A(1, BCH)
    __syncthreads();
    MMA_HALF(ACH, BCH)

    // ---- epilogue: vals + cross-wave LN (sRed aliases dead sXj)
    float2* sRed = (float2*)&sXj[0][0];   // [64 edges][4 waves]
    int nA = ntA * 16 + cl, nB = nA + 16;
    float r4A = sRow[0][nA], r5A = sRow[1][nA];
    float r4B = sRow[0][nB], r5B = sRow[1][nB];

#pragma unroll
    for (int eg = 0; eg < 4; eg++) {
#pragma unroll
        for (int r = 0; r < 4; r++) {
            int e = eg * 16 + kq * 4 + r;
            int pos = sPos[e];
            float v0 = acc[eg][0][r] + We[pos * 128 + nA];
            float v1 = acc[eg][1][r] + We[pos * 128 + nB];
            acc[eg][0][r] = v0; acc[eg][1][r] = v1;
            float s = v0 + v1, q2 = v0 * v0 + v1 * v1;
#pragma unroll
            for (int s2 = 1; s2 < 16; s2 <<= 1) {
                s  += __shfl_xor(s,  s2, 64);
                q2 += __shfl_xor(q2, s2, 64);
            }
            if (cl == 0) sRed[e * 4 + w] = make_float2(s, q2);
        }
    }
    __syncthreads();

#pragma unroll
    for (int eg = 0; eg < 4; eg++) {
#pragma unroll
        for (int r = 0; r < 4; r++) {
            int e = eg * 16 + kq * 4 + r;
            float4 pa = *(const float4*)&sRed[e * 4];
            float4 pb = *(const float4*)&sRed[e * 4 + 2];
            float s  = pa.x + pa.z + pb.x + pb.z;
            float q2 = pa.y + pa.w + pb.y + pb.w;
            float mean = s * (1.0f / 128.0f);
            float var = q2 * (1.0f / 128.0f) - mean * mean;
            float rstd = rsqrtf(var + 1e-5f);
            size_t base = OFF_HE + (size_t)(e0 + e) * 128;
            out[base + nA] = (acc[eg][0][r] - mean) * rstd * r4A + r5A;
            out[base + nB] = (acc[eg][1][r] - mean) * rstd * r4B + r5B;
        }
    }
}

// ---------------- launch ----------------
extern "C" void kernel_launch(void* const* d_in, const int* in_sizes, int n_in,
                              void* d_out, int out_size, void* d_ws, size_t ws_size,
                              hipStream_t stream) {
    (void)in_sizes; (void)n_in; (void)out_size; (void)ws_size;
    const float* X    = (const float*)d_in[0];
    const int*   S    = (const int*)d_in[1];
    const float* BB   = (const float*)d_in[2];
    const float* SC   = (const float*)d_in[3];
    const int*   chain= (const int*)d_in[4];
    const float* mask = (const float*)d_in[5];
    const float* Wn   = (const float*)d_in[6];
    const float* bn   = (const float*)d_in[7];
    const float* gn   = (const float*)d_in[8];
    const float* betan= (const float*)d_in[9];
    const float* We   = (const float*)d_in[10];
    const float* be   = (const float*)d_in[11];
    const float* ge   = (const float*)d_in[12];
    const float* betae= (const float*)d_in[13];
    float* out = (float*)d_out;

    char* ws = (char*)d_ws;
    int*   EidxW = (int*)ws;                                  // 524288 B
    float* X5    = (float*)(ws + 524288);                     // 245760 B (ends 770048)
    short* WTf   = (short*)(ws + 770048);                     // 106496 B (ends 876544)
    float* Cax   = (float*)(ws + 876544);                     // 16384 B
    float* Cay   = (float*)(ws + 892928);                     // 16384 B
    float* Caz   = (float*)(ws + 909312);                     // 16384 B (ends 925696)

    hipLaunchKernelGGL(prep_wconv_kernel, dim3(16 + 26), dim3(256), 0, stream,
                       X, X5, Cax, Cay, Caz, out, We, be, WTf);
    hipLaunchKernelGGL(knn_node_kernel, dim3(NB * NL / 4), dim3(256), 0, stream,
                       Cax, Cay, Caz, mask, S, BB, SC, Wn, bn, gn, betan, EidxW, out);
    hipLaunchKernelGGL(edge7_kernel, dim3(NB * NL * NK / 64), dim3(256), 0, stream,
                       X5, EidxW, chain, We, ge, betae, WTf, out);
}

// Round 6
// 182.049 us; speedup vs baseline: 1.1371x; 1.0155x over previous
//
#include <hip/hip_runtime.h>
#include <math.h>

#define NB 2
#define NL 2048
#define NK 32
#define NODE_F 128
#define EDGE_F 128

// output layout (float32 elements)
#define OFF_HV   0
#define OFF_HE   (NB*NL*NODE_F)                 // 524288
#define OFF_EIDX (OFF_HE + NB*NL*NK*EDGE_F)     // 17301504
#define OFF_X    (OFF_EIDX + NB*NL*NK)          // 17432576

#define ACH 7        // chunks (K=32) in half A
#define BCH 6        // chunks in half B
#define SAW 232      // sA row stride in shorts (464 B, 16B-aligned, bank-friendly)

typedef __attribute__((ext_vector_type(8))) short v8s;
typedef __attribute__((ext_vector_type(4))) float v4f;

__device__ __forceinline__ short f2bf(float f) {
    unsigned u = __float_as_uint(f);
    unsigned r = u + 0x7fffu + ((u >> 16) & 1u);
    return (short)(r >> 16);
}

#if __has_builtin(__builtin_amdgcn_exp2f)
#define EXP2F(x) __builtin_amdgcn_exp2f(x)
#else
#define EXP2F(x) __expf((x) * 0.6931471805599453f)
#endif

// pack top halves of two f32 bit-patterns (truncating f32->bf16) into one u32
__device__ __forceinline__ unsigned bfpack(float f0, float f1) {
    unsigned u0 = __float_as_uint(f0), u1 = __float_as_uint(f1);
#if __has_builtin(__builtin_amdgcn_perm)
    return __builtin_amdgcn_perm(u1, u0, 0x07060302u);  // {u1.hi16, u0.hi16}
#else
    return (u1 & 0xFFFF0000u) | (u0 >> 16);
#endif
}

// ---------------- DPP wave-min (u64) — no LDS, pure VALU ----------------
template<int CTRL>
__device__ __forceinline__ unsigned long long dpp_min_step(unsigned long long x) {
    unsigned lo = (unsigned)x, hi = (unsigned)(x >> 32);
    unsigned plo = (unsigned)__builtin_amdgcn_update_dpp((int)lo, (int)lo, CTRL, 0xF, 0xF, false);
    unsigned phi = (unsigned)__builtin_amdgcn_update_dpp((int)hi, (int)hi, CTRL, 0xF, 0xF, false);
    unsigned long long p = (((unsigned long long)phi) << 32) | plo;
    return p < x ? p : x;
}
__device__ __forceinline__ unsigned long long wave_min_u64_dpp(unsigned long long x) {
    x = dpp_min_step<0xB1>(x);    // quad_perm [1,0,3,2] : pair min
    x = dpp_min_step<0x4E>(x);    // quad_perm [2,3,0,1] : quad min
    x = dpp_min_step<0x141>(x);   // row_half_mirror     : 8-group min
    x = dpp_min_step<0x140>(x);   // row_mirror          : row(16) min
    x = dpp_min_step<0x142>(x);   // row_bcast15         : rows 1,3 get 2-row min
    x = dpp_min_step<0x143>(x);   // row_bcast31         : lanes 32-63 get global
    return x;                     // lane 63 holds the global min
}

// ---------------- helpers ----------------
__device__ __forceinline__ void cross3(const float a[3], const float b[3], float c[3]) {
    c[0] = a[1]*b[2] - a[2]*b[1];
    c[1] = a[2]*b[0] - a[0]*b[2];
    c[2] = a[0]*b[1] - a[1]*b[0];
}
__device__ __forceinline__ float dot3(const float a[3], const float b[3]) {
    return a[0]*b[0] + a[1]*b[1] + a[2]*b[2];
}
__device__ float dihedral_f(const float p0[3], const float p1[3],
                            const float p2[3], const float p3[3]) {
    float u0[3], u1[3], u2[3];
    for (int d = 0; d < 3; d++) {
        u0[d] = p2[d] - p1[d];
        u1[d] = p0[d] - p1[d];
        u2[d] = p3[d] - p2[d];
    }
    float n1[3], n2[3], c12[3];
    cross3(u0, u1, n1);
    cross3(u0, u2, n2);
    cross3(u1, u2, c12);
    float l1 = sqrtf(dot3(n1, n1));
    float l2 = sqrtf(dot3(n2, n2));
    float cosang = dot3(n1, n2) / (l1 * l2);
    float s = dot3(c12, u0);
    float sgn = (s > 0.f) ? 1.f : ((s < 0.f) ? -1.f : 0.f);
    float r = sgn * acosf(cosang);
    return isnan(r) ? 0.f : r;
}

// ---------------- KNN macros ----------------
#define KNN_QMIN(Q) {                                                                  \
    unsigned long long a_ = key[(Q)*8+0] < key[(Q)*8+1] ? key[(Q)*8+0] : key[(Q)*8+1]; \
    unsigned long long b_ = key[(Q)*8+2] < key[(Q)*8+3] ? key[(Q)*8+2] : key[(Q)*8+3]; \
    unsigned long long c_ = key[(Q)*8+4] < key[(Q)*8+5] ? key[(Q)*8+4] : key[(Q)*8+5]; \
    unsigned long long d_ = key[(Q)*8+6] < key[(Q)*8+7] ? key[(Q)*8+6] : key[(Q)*8+7]; \
    a_ = a_ < b_ ? a_ : b_; c_ = c_ < d_ ? c_ : d_;                                    \
    qm[(Q)] = a_ < c_ ? a_ : c_; }

#define KNN_STEP(Q) {                                                                  \
    _Pragma("unroll")                                                                  \
    for (int i_ = 0; i_ < 8; i_++)                                                     \
        key[(Q)*8+i_] = (me && tstar == (Q)*8+i_) ? ~0ull : key[(Q)*8+i_];             \
    KNN_QMIN(Q) }

// ---------------- kernel 0: fused {knn_node blocks 0..1023}{prep 1024..1039}{wconv 1040..1065} ----------------
// All three parts are mutually independent: knn reads Ca directly from X (staged in LDS).
__global__ __launch_bounds__(256) void fused_pre_kernel(const float* __restrict__ X,
                                                        const float* __restrict__ mask,
                                                        const int* __restrict__ S,
                                                        const float* __restrict__ BB,
                                                        const float* __restrict__ SC,
                                                        const float* __restrict__ Wn,
                                                        const float* __restrict__ bn,
                                                        const float* __restrict__ gn,
                                                        const float* __restrict__ betan,
                                                        const float* __restrict__ We,
                                                        const float* __restrict__ be,
                                                        float* __restrict__ X5,
                                                        short* __restrict__ WTf,
                                                        int* __restrict__ EidxW,
                                                        float* __restrict__ out) {
    __shared__ float sCa[NL * 3];   // 24 KB : this block's batch Ca coords
    int blk = blockIdx.x;
    int tid = threadIdx.x;

    if (blk >= 1024) {
        if (blk < 1040) {
            // ---- prep: X5 + X passthrough ----
            int row = (blk - 1024) * 256 + tid;
            float v[12];
#pragma unroll
            for (int t = 0; t < 12; t++) v[t] = X[row * 12 + t];
#pragma unroll
            for (int t = 0; t < 12; t++) out[OFF_X + row * 12 + t] = v[t];
            float bv[3], cv[3], cr[3];
            for (int d = 0; d < 3; d++) { bv[d] = v[3+d] - v[d]; cv[d] = v[6+d] - v[3+d]; }
            cross3(bv, cv, cr);
            float* x5 = X5 + row * 15;
#pragma unroll
            for (int t = 0; t < 12; t++) x5[t] = v[t];
            for (int d = 0; d < 3; d++)
                x5[12 + d] = -0.58273431f * cr[d] + 0.56802827f * bv[d] - 0.54067466f * cv[d] + v[3+d];
        } else {
            // ---- wconv: k<400 RBF rows We[65+k]; 400..402 = We[465..467]; 403 = be; else 0 ----
            int t = (blk - 1040) * 256 + tid;
            if (t >= 13 * 8 * 64) return;
            int lane = t & 63;
            int nt = (t >> 6) & 7;
            int ch = t >> 9;
            int n = nt * 16 + (lane & 15);
            int kbase = ch * 32 + (lane >> 4) * 8;
            short* dst = WTf + (size_t)t * 8;
#pragma unroll
            for (int j = 0; j < 8; j++) {
                int k = kbase + j;
                float f;
                if (k < 403) f = We[(65 + k) * 128 + n];
                else if (k == 403) f = be[n];
                else f = 0.f;
                dst[j] = f2bf(f);
            }
        }
        return;
    }

    // ---- knn + node: 4 rows per block ----
    int w = tid >> 6, l = tid & 63;
    int row = blk * 4 + w;
    int b = row / NL;
    int base = b * NL;

    // stage this batch's Ca into LDS (strided X reads, once per block)
    for (int idx = tid; idx < NL; idx += 256) {
        const float* xp = X + (size_t)(base + idx) * 12 + 3;
        sCa[idx * 3 + 0] = xp[0];
        sCa[idx * 3 + 1] = xp[1];
        sCa[idx * 3 + 2] = xp[2];
    }

    // node features + LN (hides staging latency; independent of sCa)
    {
        int f0 = l, f1 = 64 + l;
        int s = S[row];
        float a0 = bn[f0] + Wn[s * NODE_F + f0];
        float a1 = bn[f1] + Wn[s * NODE_F + f1];
#pragma unroll
        for (int t = 0; t < 6; t++) {
            float x = BB[row * 6 + t];
            a0 += x * Wn[(21 + t) * NODE_F + f0];
            a1 += x * Wn[(21 + t) * NODE_F + f1];
        }
#pragma unroll
        for (int t = 0; t < 8; t++) {
            float x = SC[row * 8 + t];
            a0 += x * Wn[(27 + t) * NODE_F + f0];
            a1 += x * Wn[(27 + t) * NODE_F + f1];
        }
        float sm = a0 + a1;
#pragma unroll
        for (int st = 1; st < 64; st <<= 1) sm += __shfl_xor(sm, st, 64);
        float mean = sm * (1.0f / 128.0f);
        float d0 = a0 - mean, d1 = a1 - mean;
        float q = d0 * d0 + d1 * d1;
#pragma unroll
        for (int st = 1; st < 64; st <<= 1) q += __shfl_xor(q, st, 64);
        float rstd = 1.0f / sqrtf(q * (1.0f / 128.0f) + 1e-5f);
        out[OFF_HV + row * NODE_F + f0] = d0 * rstd * gn[f0] + betan[f0];
        out[OFF_HV + row * NODE_F + f1] = d1 * rstd * gn[f1] + betan[f1];
    }
    __syncthreads();

    const float* mrow = mask + base;
    int lrow = row - base;
    float cx = sCa[lrow * 3 + 0], cy = sCa[lrow * 3 + 1], cz = sCa[lrow * 3 + 2];
    float mi = mrow[lrow];

    float K[32];
    float lmax = 0.0f;
#pragma unroll
    for (int t = 0; t < 32; t++) {
        int j = t * 64 + l;
        float dx = __fsub_rn(cx, sCa[j * 3 + 0]);
        float dy = __fsub_rn(cy, sCa[j * 3 + 1]);
        float dz = __fsub_rn(cz, sCa[j * 3 + 2]);
        float ss = __fadd_rn(__fadd_rn(__fadd_rn(__fmul_rn(dx, dx), __fmul_rn(dy, dy)),
                                       __fmul_rn(dz, dz)), 1e-6f);
        float d = __fmul_rn(__fmul_rn(mi, mrow[j]), __fsqrt_rn(ss));
        K[t] = d;
        lmax = fmaxf(lmax, d);
    }
#pragma unroll
    for (int s = 1; s < 64; s <<= 1) lmax = fmaxf(lmax, __shfl_xor(lmax, s, 64));
#pragma unroll
    for (int t = 0; t < 32; t++) {
        int j = t * 64 + l;
        float m2 = __fmul_rn(mi, mrow[j]);
        K[t] = __fadd_rn(K[t], __fmul_rn(__fmul_rn(2.0f, __fsub_rn(1.0f, m2)), lmax));
    }

    unsigned long long key[32];
#pragma unroll
    for (int t = 0; t < 32; t++)
        key[t] = (((unsigned long long)__float_as_uint(K[t])) << 32) | (unsigned)(t * 64 + l);

    unsigned long long qm[4];
    KNN_QMIN(0) KNN_QMIN(1) KNN_QMIN(2) KNN_QMIN(3)

    int selj = 0;
#pragma unroll 1
    for (int r = 0; r < NK; r++) {
        unsigned long long m01 = qm[0] < qm[1] ? qm[0] : qm[1];
        unsigned long long m23 = qm[2] < qm[3] ? qm[2] : qm[3];
        unsigned long long g = m01 < m23 ? m01 : m23;
        g = wave_min_u64_dpp(g);
        unsigned j = (unsigned)__builtin_amdgcn_readlane((int)(unsigned)g, 63);
        if (l == r) selj = (int)j;
        bool me = ((j & 63u) == (unsigned)l);
        int tstar = (int)(j >> 6);
        switch (tstar >> 3) {
            case 0: KNN_STEP(0) break;
            case 1: KNN_STEP(1) break;
            case 2: KNN_STEP(2) break;
            default: KNN_STEP(3) break;
        }
    }
    if (l < NK) {
        EidxW[row * NK + l] = selj;
        out[OFF_EIDX + row * NK + l] = (float)selj;
    }
}

// ---------------- kernel 1: edge8 — A in LDS, geometric-recurrence RBF (2 exp/octet) ----------------
__global__ __launch_bounds__(256, 4) void edge8_kernel(const float* __restrict__ X5,
                                                       const int* __restrict__ Eidx,
                                                       const int* __restrict__ chain,
                                                       const float* __restrict__ We,
                                                       const float* __restrict__ ge,
                                                       const float* __restrict__ betae,
                                                       const short* __restrict__ WTf,
                                                       float* __restrict__ out) {
    __shared__ short sA[64 * SAW];        // 29696 B : bf16 A-matrix, one K-half at a time
    __shared__ float sXj[64][17];         // 4352 B  : aliased by sRed in the epilogue
    __shared__ float sXi[2][15];          // 120 B
    __shared__ float sRow[2][128];        // 1024 B : ge, betae
    __shared__ int   sJ[64];              // 256 B
    __shared__ int   sPos[64];            // 256 B
    __shared__ float sEt[64], sPhi[64], sPsi[64];   // 768 B   (total ~36.5 KB -> 4 blocks/CU)

    int tid = threadIdx.x;
    int e0 = blockIdx.x * 64;
    int b = e0 / (NL * NK);
    int i0 = (e0 / NK) % NL;
    int lane = tid & 63, w = tid >> 6;

    // ---- phase 0a: indices + small tables
    if (tid < 64) sJ[tid] = Eidx[e0 + tid];
    if (tid < 30) sXi[tid / 15][tid % 15] = X5[(b * NL + i0 + tid / 15) * 15 + (tid % 15)];
    if (tid >= 128 && tid < 128 + 128) {
        int n2 = tid - 128;
        sRow[0][n2] = ge[n2];
        sRow[1][n2] = betae[n2];
    }
    __syncthreads();

    // ---- phase 0b: gather neighbor coords, pos/type
    for (int t = tid; t < 64 * 15; t += 256) {
        int e = t / 15, c2 = t % 15;
        sXj[e][c2] = X5[(b * NL + sJ[e]) * 15 + c2];
    }
    if (tid < 64) {
        int e = tid;
        int i = i0 + (e >> 5);
        int j = sJ[e];
        int off = j - i + 32;
        off = off < 0 ? 0 : (off > 64 ? 64 : off);
        sPos[e] = off;
        sEt[e] = (chain[b * NL + j] == chain[b * NL + i]) ? 2.0f : 1.0f;
    }
    __syncthreads();

    // ---- phase 0c: dihedrals on threads 0..127 (needs sXj)
    if (tid < 128) {
        int e = tid & 63;
        const float* xi = sXi[e >> 5];
        const float* xj = sXj[e];
        if (tid < 64) sPhi[e] = dihedral_f(&xi[6], &xj[0], &xj[3], &xj[6]);
        else          sPsi[e] = dihedral_f(&xi[0], &xi[3], &xi[6], &xj[0]);
    }

    // ---- A-matrix generator: geometric recurrence.
    // v_m = exp2(Ac*(ee-m*D)^2), D = 4/3:  v_{m+1} = v_m*g_m,  g_0 = exp2(K1*ee)*R,  g_{m+1} = g_m*R^2
    // with K1 = -2*Ac*D, R = 2^(Ac*D^2).  2 exp + 17 mul per octet vs 8 exp + 24 fma/add.
    const float Ac  = -0.92332482616893658f;
    const float K1c = 2.46219953645049755f;                 // -2*Ac*(4/3)
    const float Rc  = EXP2F(-1.64146635763366503f);         // 2^(Ac*(4/3)^2)
    const float R2c = Rc * Rc;
    int eg_ = w * 16 + (lane & 15);
    int q_ = lane >> 4;
    const float* xiG = sXi[eg_ >> 5];
    const float* xjG = sXj[eg_];
    short* rowp = sA + eg_ * SAW;
    float hfq = (float)(q_ & 1);              // o&1 == q&1 (o = q + 4t)

#define GEN_A(hh, CNT)                                                         \
    {                                                                          \
        _Pragma("unroll")                                                      \
        for (int t = 0; t < (CNT); t++) {                                      \
            int o = q_ + t * 4;                                                \
            int kg = (hh) * 224 + o * 8;                                       \
            int pair = kg >> 4;                                                \
            union { unsigned u[4]; v8s v; } au;                                \
            if (pair >= 25) {                                                  \
                if ((hh) == 1 && o == 22) {   /* kg==400: affine slots */      \
                    au.u[0] = bfpack(sEt[eg_], sPhi[eg_]);                     \
                    au.u[1] = bfpack(sPsi[eg_], 1.0f);                         \
                    au.u[2] = 0; au.u[3] = 0;                                  \
                } else {                                                       \
                    au.u[0] = 0; au.u[1] = 0; au.u[2] = 0; au.u[3] = 0;        \
                }                                                              \
            } else {                                                           \
                int a = pair / 5, cc = pair - a * 5;                           \
                float dx = xiG[a*3+0] - xjG[cc*3+0];                           \
                float dy = xiG[a*3+1] - xjG[cc*3+1];                           \
                float dz = xiG[a*3+2] - xjG[cc*3+2];                           \
                float d = sqrtf(dx*dx + dy*dy + dz*dz + 1e-6f);                \
                float ee = fminf(__fmaf_rn(hfq, -10.666666666666666f, d), 40.f); \
                float r0 = EXP2F(Ac * ee * ee);                                \
                float g  = EXP2F(K1c * ee) * Rc;                               \
                float r1 = r0 * g; g *= R2c;                                   \
                float r2 = r1 * g; g *= R2c;                                   \
                float r3 = r2 * g; g *= R2c;                                   \
                float r4 = r3 * g; g *= R2c;                                   \
                float r5 = r4 * g; g *= R2c;                                   \
                float r6 = r5 * g; g *= R2c;                                   \
                float r7 = r6 * g;                                             \
                au.u[0] = bfpack(r0, r1);                                      \
                au.u[1] = bfpack(r2, r3);                                      \
                au.u[2] = bfpack(r4, r5);                                      \
                au.u[3] = bfpack(r6, r7);                                      \
            }                                                                  \
            *(v8s*)(rowp + o * 8) = au.v;                                      \
        }                                                                      \
    }

    GEN_A(0, ACH)
    __syncthreads();

    // ---- MFMA: waves split N (2 nt tiles each); A from LDS, B from L2 (read once per block)
    int cl = lane & 15, kq = lane >> 4;
    int ntA = 2 * w, ntB = ntA + 1;
    const char* sAc = (const char*)sA;
    int abase0 = cl * (SAW * 2) + kq * 16;

    v4f acc[4][2];
#pragma unroll
    for (int eg = 0; eg < 4; eg++) { acc[eg][0] = (v4f){0.f,0.f,0.f,0.f}; acc[eg][1] = (v4f){0.f,0.f,0.f,0.f}; }

#define MMA_HALF(CHBASE, CNT)                                                  \
    {                                                                          \
        _Pragma("unroll 2")                                                    \
        for (int chl = 0; chl < (CNT); chl++) {                                \
            const v8s* gb = (const v8s*)WTf + ((size_t)((CHBASE) + chl) * 512 + lane); \
            v8s b0 = gb[ntA * 64];                                             \
            v8s b1 = gb[ntB * 64];                                             \
            int ab = abase0 + chl * 64;                                        \
            v8s a0 = *(const v8s*)(sAc + ab);                                  \
            v8s a1 = *(const v8s*)(sAc + ab + 16 * (SAW * 2));                 \
            v8s a2 = *(const v8s*)(sAc + ab + 32 * (SAW * 2));                 \
            v8s a3 = *(const v8s*)(sAc + ab + 48 * (SAW * 2));                 \
            acc[0][0] = __builtin_amdgcn_mfma_f32_16x16x32_bf16(a0, b0, acc[0][0], 0, 0, 0); \
            acc[0][1] = __builtin_amdgcn_mfma_f32_16x16x32_bf16(a0, b1, acc[0][1], 0, 0, 0); \
            acc[1][0] = __builtin_amdgcn_mfma_f32_16x16x32_bf16(a1, b0, acc[1][0], 0, 0, 0); \
            acc[1][1] = __builtin_amdgcn_mfma_f32_16x16x32_bf16(a1, b1, acc[1][1], 0, 0, 0); \
            acc[2][0] = __builtin_amdgcn_mfma_f32_16x16x32_bf16(a2, b0, acc[2][0], 0, 0, 0); \
            acc[2][1] = __builtin_amdgcn_mfma_f32_16x16x32_bf16(a2, b1, acc[2][1], 0, 0, 0); \
            acc[3][0] = __builtin_amdgcn_mfma_f32_16x16x32_bf16(a3, b0, acc[3][0], 0, 0, 0); \
            acc[3][1] = __builtin_amdgcn_mfma_f32_16x16x32_bf16(a3, b1, acc[3][1], 0, 0, 0); \
        }                                                                      \
    }

    MMA_HALF(0, ACH)
    __syncthreads();          // all waves done reading sA half A
    GEN_A(1, BCH)
    __syncthreads();
    MMA_HALF(ACH, BCH)

    // ---- epilogue: vals + cross-wave LN (sRed aliases dead sXj)
    float2* sRed = (float2*)&sXj[0][0];   // [64 edges][4 waves]
    int nA = ntA * 16 + cl, nB = nA + 16;
    float r4A = sRow[0][nA], r5A = sRow[1][nA];
    float r4B = sRow[0][nB], r5B = sRow[1][nB];

#pragma unroll
    for (int eg = 0; eg < 4; eg++) {
#pragma unroll
        for (int r = 0; r < 4; r++) {
            int e = eg * 16 + kq * 4 + r;
            int pos = sPos[e];
            float v0 = acc[eg][0][r] + We[pos * 128 + nA];
            float v1 = acc[eg][1][r] + We[pos * 128 + nB];
            acc[eg][0][r] = v0; acc[eg][1][r] = v1;
            float s = v0 + v1, q2 = v0 * v0 + v1 * v1;
#pragma unroll
            for (int s2 = 1; s2 < 16; s2 <<= 1) {
                s  += __shfl_xor(s,  s2, 64);
                q2 += __shfl_xor(q2, s2, 64);
            }
            if (cl == 0) sRed[e * 4 + w] = make_float2(s, q2);
        }
    }
    __syncthreads();

#pragma unroll
    for (int eg = 0; eg < 4; eg++) {
#pragma unroll
        for (int r = 0; r < 4; r++) {
            int e = eg * 16 + kq * 4 + r;
            float4 pa = *(const float4*)&sRed[e * 4];
            float4 pb = *(const float4*)&sRed[e * 4 + 2];
            float s  = pa.x + pa.z + pb.x + pb.z;
            float q2 = pa.y + pa.w + pb.y + pb.w;
            float mean = s * (1.0f / 128.0f);
            float var = q2 * (1.0f / 128.0f) - mean * mean;
            float rstd = rsqrtf(var + 1e-5f);
            size_t base = OFF_HE + (size_t)(e0 + e) * 128;
            out[base + nA] = (acc[eg][0][r] - mean) * rstd * r4A + r5A;
            out[base + nB] = (acc[eg][1][r] - mean) * rstd * r4B + r5B;
        }
    }
}

// ---------------- launch ----------------
extern "C" void kernel_launch(void* const* d_in, const int* in_sizes, int n_in,
                              void* d_out, int out_size, void* d_ws, size_t ws_size,
                              hipStream_t stream) {
    (void)in_sizes; (void)n_in; (void)out_size; (void)ws_size;
    const float* X    = (const float*)d_in[0];
    const int*   S    = (const int*)d_in[1];
    const float* BB   = (const float*)d_in[2];
    const float* SC   = (const float*)d_in[3];
    const int*   chain= (const int*)d_in[4];
    const float* mask = (const float*)d_in[5];
    const float* Wn   = (const float*)d_in[6];
    const float* bn   = (const float*)d_in[7];
    const float* gn   = (const float*)d_in[8];
    const float* betan= (const float*)d_in[9];
    const float* We   = (const float*)d_in[10];
    const float* be   = (const float*)d_in[11];
    const float* ge   = (const float*)d_in[12];
    const float* betae= (const float*)d_in[13];
    float* out = (float*)d_out;

    char* ws = (char*)d_ws;
    int*   EidxW = (int*)ws;                                  // 524288 B
    float* X5    = (float*)(ws + 524288);                     // 245760 B (ends 770048)
    short* WTf   = (short*)(ws + 770048);                     // 106496 B (ends 876544)

    hipLaunchKernelGGL(fused_pre_kernel, dim3(1024 + 16 + 26), dim3(256), 0, stream,
                       X, mask, S, BB, SC, Wn, bn, gn, betan, We, be,
                       X5, WTf, EidxW, out);
    hipLaunchKernelGGL(edge8_kernel, dim3(NB * NL * NK / 64), dim3(256), 0, stream,
                       X5, EidxW, chain, We, ge, betae, WTf, out);
}

// Round 7
// 159.624 us; speedup vs baseline: 1.2969x; 1.1405x over previous
//
#include <hip/hip_runtime.h>
#include <math.h>

#define NB 2
#define NL 2048
#define NK 32
#define NODE_F 128
#define EDGE_F 128

// output layout (float32 elements)
#define OFF_HV   0
#define OFF_HE   (NB*NL*NODE_F)                 // 524288
#define OFF_EIDX (OFF_HE + NB*NL*NK*EDGE_F)     // 17301504
#define OFF_X    (OFF_EIDX + NB*NL*NK)          // 17432576

#define ACH 7        // chunks (K=32) in half A
#define BCH 6        // chunks in half B
#define SAW 232      // sA row stride in shorts (464 B, 16B-aligned, bank-friendly)

typedef __attribute__((ext_vector_type(8))) short v8s;
typedef __attribute__((ext_vector_type(4))) float v4f;

__device__ __forceinline__ short f2bf(float f) {
    unsigned u = __float_as_uint(f);
    unsigned r = u + 0x7fffu + ((u >> 16) & 1u);
    return (short)(r >> 16);
}

#if __has_builtin(__builtin_amdgcn_exp2f)
#define EXP2F(x) __builtin_amdgcn_exp2f(x)
#else
#define EXP2F(x) __expf((x) * 0.6931471805599453f)
#endif

// pack top halves of two f32 bit-patterns (truncating f32->bf16) into one u32
__device__ __forceinline__ unsigned bfpack(float f0, float f1) {
    unsigned u0 = __float_as_uint(f0), u1 = __float_as_uint(f1);
#if __has_builtin(__builtin_amdgcn_perm)
    return __builtin_amdgcn_perm(u1, u0, 0x07060302u);  // {u1.hi16, u0.hi16}
#else
    return (u1 & 0xFFFF0000u) | (u0 >> 16);
#endif
}

// ---------------- DPP wave-min (u32) — no LDS, pure VALU; lane 63 gets global min ----------------
template<int CTRL>
__device__ __forceinline__ unsigned dpp_min_u32_step(unsigned x) {
    unsigned p = (unsigned)__builtin_amdgcn_update_dpp((int)x, (int)x, CTRL, 0xF, 0xF, false);
    return p < x ? p : x;
}
__device__ __forceinline__ unsigned wave_min_u32_dpp(unsigned x) {
    x = dpp_min_u32_step<0xB1>(x);    // quad_perm [1,0,3,2]
    x = dpp_min_u32_step<0x4E>(x);    // quad_perm [2,3,0,1]
    x = dpp_min_u32_step<0x141>(x);   // row_half_mirror
    x = dpp_min_u32_step<0x140>(x);   // row_mirror
    x = dpp_min_u32_step<0x142>(x);   // row_bcast15
    x = dpp_min_u32_step<0x143>(x);   // row_bcast31
    return x;                         // lane 63 holds the global min
}

// ---------------- helpers ----------------
__device__ __forceinline__ void cross3(const float a[3], const float b[3], float c[3]) {
    c[0] = a[1]*b[2] - a[2]*b[1];
    c[1] = a[2]*b[0] - a[0]*b[2];
    c[2] = a[0]*b[1] - a[1]*b[0];
}
__device__ __forceinline__ float dot3(const float a[3], const float b[3]) {
    return a[0]*b[0] + a[1]*b[1] + a[2]*b[2];
}
__device__ float dihedral_f(const float p0[3], const float p1[3],
                            const float p2[3], const float p3[3]) {
    float u0[3], u1[3], u2[3];
    for (int d = 0; d < 3; d++) {
        u0[d] = p2[d] - p1[d];
        u1[d] = p0[d] - p1[d];
        u2[d] = p3[d] - p2[d];
    }
    float n1[3], n2[3], c12[3];
    cross3(u0, u1, n1);
    cross3(u0, u2, n2);
    cross3(u1, u2, c12);
    float l1 = sqrtf(dot3(n1, n1));
    float l2 = sqrtf(dot3(n2, n2));
    float cosang = dot3(n1, n2) / (l1 * l2);
    float s = dot3(c12, u0);
    float sgn = (s > 0.f) ? 1.f : ((s < 0.f) ? -1.f : 0.f);
    float r = sgn * acosf(cosang);
    return isnan(r) ? 0.f : r;
}

// ---------------- kernel 0: fused {knn_node blocks 0..1023}{prep 1024..1039}{wconv 1040..1065} ----------------
__global__ __launch_bounds__(256) void fused_pre_kernel(const float* __restrict__ X,
                                                        const float* __restrict__ mask,
                                                        const int* __restrict__ S,
                                                        const float* __restrict__ BB,
                                                        const float* __restrict__ SC,
                                                        const float* __restrict__ Wn,
                                                        const float* __restrict__ bn,
                                                        const float* __restrict__ gn,
                                                        const float* __restrict__ betan,
                                                        const float* __restrict__ We,
                                                        const float* __restrict__ be,
                                                        float* __restrict__ X5,
                                                        short* __restrict__ WTf,
                                                        int* __restrict__ EidxW,
                                                        float* __restrict__ out) {
    __shared__ float sCa[NL * 3];               // 24 KB : this block's batch Ca coords
    __shared__ unsigned long long sSel[4][64];  // 2 KB  : per-wave candidate slots
    int blk = blockIdx.x;
    int tid = threadIdx.x;

    if (blk >= 1024) {
        if (blk < 1040) {
            // ---- prep: X5 + X passthrough ----
            int row = (blk - 1024) * 256 + tid;
            float v[12];
#pragma unroll
            for (int t = 0; t < 12; t++) v[t] = X[row * 12 + t];
#pragma unroll
            for (int t = 0; t < 12; t++) out[OFF_X + row * 12 + t] = v[t];
            float bv[3], cv[3], cr[3];
            for (int d = 0; d < 3; d++) { bv[d] = v[3+d] - v[d]; cv[d] = v[6+d] - v[3+d]; }
            cross3(bv, cv, cr);
            float* x5 = X5 + row * 15;
#pragma unroll
            for (int t = 0; t < 12; t++) x5[t] = v[t];
            for (int d = 0; d < 3; d++)
                x5[12 + d] = -0.58273431f * cr[d] + 0.56802827f * bv[d] - 0.54067466f * cv[d] + v[3+d];
        } else {
            // ---- wconv: k<400 RBF rows We[65+k]; 400..402 = We[465..467]; 403 = be; else 0 ----
            int t = (blk - 1040) * 256 + tid;
            if (t >= 13 * 8 * 64) return;
            int lane = t & 63;
            int nt = (t >> 6) & 7;
            int ch = t >> 9;
            int n = nt * 16 + (lane & 15);
            int kbase = ch * 32 + (lane >> 4) * 8;
            short* dst = WTf + (size_t)t * 8;
#pragma unroll
            for (int j = 0; j < 8; j++) {
                int k = kbase + j;
                float f;
                if (k < 403) f = We[(65 + k) * 128 + n];
                else if (k == 403) f = be[n];
                else f = 0.f;
                dst[j] = f2bf(f);
            }
        }
        return;
    }

    // ---- knn + node: 4 rows per block ----
    int w = tid >> 6, l = tid & 63;
    int row = blk * 4 + w;
    int b = row / NL;
    int base = b * NL;

    // stage this batch's Ca into LDS (once per block)
    for (int idx = tid; idx < NL; idx += 256) {
        const float* xp = X + (size_t)(base + idx) * 12 + 3;
        sCa[idx * 3 + 0] = xp[0];
        sCa[idx * 3 + 1] = xp[1];
        sCa[idx * 3 + 2] = xp[2];
    }

    // node features + LN (hides staging latency; independent of sCa)
    {
        int f0 = l, f1 = 64 + l;
        int s = S[row];
        float a0 = bn[f0] + Wn[s * NODE_F + f0];
        float a1 = bn[f1] + Wn[s * NODE_F + f1];
#pragma unroll
        for (int t = 0; t < 6; t++) {
            float x = BB[row * 6 + t];
            a0 += x * Wn[(21 + t) * NODE_F + f0];
            a1 += x * Wn[(21 + t) * NODE_F + f1];
        }
#pragma unroll
        for (int t = 0; t < 8; t++) {
            float x = SC[row * 8 + t];
            a0 += x * Wn[(27 + t) * NODE_F + f0];
            a1 += x * Wn[(27 + t) * NODE_F + f1];
        }
        float sm = a0 + a1;
#pragma unroll
        for (int st = 1; st < 64; st <<= 1) sm += __shfl_xor(sm, st, 64);
        float mean = sm * (1.0f / 128.0f);
        float d0 = a0 - mean, d1 = a1 - mean;
        float q = d0 * d0 + d1 * d1;
#pragma unroll
        for (int st = 1; st < 64; st <<= 1) q += __shfl_xor(q, st, 64);
        float rstd = 1.0f / sqrtf(q * (1.0f / 128.0f) + 1e-5f);
        out[OFF_HV + row * NODE_F + f0] = d0 * rstd * gn[f0] + betan[f0];
        out[OFF_HV + row * NODE_F + f1] = d1 * rstd * gn[f1] + betan[f1];
    }
    __syncthreads();

    const float* mrow = mask + base;
    int lrow = row - base;
    float cx = sCa[lrow * 3 + 0], cy = sCa[lrow * 3 + 1], cz = sCa[lrow * 3 + 2];
    float mi = mrow[lrow];

    // ---- adjusted distances (bit-identical to previous rounds) ----
    float K[32];
    float lmax = 0.0f;
#pragma unroll
    for (int t = 0; t < 32; t++) {
        int j = t * 64 + l;
        float dx = __fsub_rn(cx, sCa[j * 3 + 0]);
        float dy = __fsub_rn(cy, sCa[j * 3 + 1]);
        float dz = __fsub_rn(cz, sCa[j * 3 + 2]);
        float ss = __fadd_rn(__fadd_rn(__fadd_rn(__fmul_rn(dx, dx), __fmul_rn(dy, dy)),
                                       __fmul_rn(dz, dz)), 1e-6f);
        float d = __fmul_rn(__fmul_rn(mi, mrow[j]), __fsqrt_rn(ss));
        K[t] = d;
        lmax = fmaxf(lmax, d);
    }
#pragma unroll
    for (int s = 1; s < 64; s <<= 1) lmax = fmaxf(lmax, __shfl_xor(lmax, s, 64));
#pragma unroll
    for (int t = 0; t < 32; t++) {
        int j = t * 64 + l;
        float m2 = __fmul_rn(mi, mrow[j]);
        K[t] = __fadd_rn(K[t], __fmul_rn(__fmul_rn(2.0f, __fsub_rn(1.0f, m2)), lmax));
    }

    // ---- radix binary-search for tau: count(K <= tau) in [32, 64] ----
    unsigned lo_ = 0u, hi_ = 0x7f7fffffu, tau = 0x7f7fffffu;
#pragma unroll 1
    for (int it = 0; it < 31; it++) {
        unsigned mid = (lo_ + hi_) >> 1;
        float tf = __uint_as_float(mid);
        int c = 0;
#pragma unroll
        for (int t = 0; t < 32; t++) c += __popcll(__ballot(K[t] <= tf));
        if (c >= 32) {
            tau = mid;
            if (c <= 64) break;
            hi_ = mid - 1;
        } else {
            lo_ = mid + 1;
        }
    }
    float tauf = __uint_as_float(tau);

    // ---- compact candidates into slots (slot order == ascending j -> exact tie semantics) ----
    sSel[w][l] = ~0ull;
    int cbase = 0;
#pragma unroll
    for (int t = 0; t < 32; t++) {
        bool q = (K[t] <= tauf);
        unsigned long long m = __ballot(q);
        int pos = cbase + __popcll(m & ((1ull << l) - 1ull));
        if (q && pos < 64)
            sSel[w][pos] = (((unsigned long long)__float_as_uint(K[t])) << 32)
                           | (unsigned)(t * 64 + l);
        cbase += __popcll(m);
    }

    // ---- 32 extract-min rounds over 64 candidates (1 key/lane) ----
    unsigned long long key = sSel[w][l];
    int selj = 0;
#pragma unroll 1
    for (int r = 0; r < NK; r++) {
        unsigned hi = (unsigned)(key >> 32);
        unsigned gh = (unsigned)__builtin_amdgcn_readlane((int)wave_min_u32_dpp(hi), 63);
        unsigned long long mask_ = __ballot(hi == gh);
        int wl = __ffsll((unsigned long long)mask_) - 1;   // first lane == smallest slot == smallest j
        unsigned j = (unsigned)__builtin_amdgcn_readlane((int)(unsigned)key, wl);
        if (l == r) selj = (int)j;
        if (l == wl) key = ~0ull;
    }
    if (l < NK) {
        EidxW[row * NK + l] = selj;
        out[OFF_EIDX + row * NK + l] = (float)selj;
    }
}

// ---------------- kernel 1: edge8 — A in LDS, geometric-recurrence RBF (2 exp/octet) ----------------
__global__ __launch_bounds__(256, 4) void edge8_kernel(const float* __restrict__ X5,
                                                       const int* __restrict__ Eidx,
                                                       const int* __restrict__ chain,
                                                       const float* __restrict__ We,
                                                       const float* __restrict__ ge,
                                                       const float* __restrict__ betae,
                                                       const short* __restrict__ WTf,
                                                       float* __restrict__ out) {
    __shared__ short sA[64 * SAW];        // 29696 B : bf16 A-matrix, one K-half at a time
    __shared__ float sXj[64][17];         // 4352 B  : aliased by sRed in the epilogue
    __shared__ float sXi[2][15];          // 120 B
    __shared__ float sRow[2][128];        // 1024 B : ge, betae
    __shared__ int   sJ[64];              // 256 B
    __shared__ int   sPos[64];            // 256 B
    __shared__ float sEt[64], sPhi[64], sPsi[64];   // 768 B

    int tid = threadIdx.x;
    int e0 = blockIdx.x * 64;
    int b = e0 / (NL * NK);
    int i0 = (e0 / NK) % NL;
    int lane = tid & 63, w = tid >> 6;

    // ---- phase 0a: indices + small tables
    if (tid < 64) sJ[tid] = Eidx[e0 + tid];
    if (tid < 30) sXi[tid / 15][tid % 15] = X5[(b * NL + i0 + tid / 15) * 15 + (tid % 15)];
    if (tid >= 128 && tid < 128 + 128) {
        int n2 = tid - 128;
        sRow[0][n2] = ge[n2];
        sRow[1][n2] = betae[n2];
    }
    __syncthreads();

    // ---- phase 0b: gather neighbor coords, pos/type
    for (int t = tid; t < 64 * 15; t += 256) {
        int e = t / 15, c2 = t % 15;
        sXj[e][c2] = X5[(b * NL + sJ[e]) * 15 + c2];
    }
    if (tid < 64) {
        int e = tid;
        int i = i0 + (e >> 5);
        int j = sJ[e];
        int off = j - i + 32;
        off = off < 0 ? 0 : (off > 64 ? 64 : off);
        sPos[e] = off;
        sEt[e] = (chain[b * NL + j] == chain[b * NL + i]) ? 2.0f : 1.0f;
    }
    __syncthreads();

    // ---- phase 0c: dihedrals on threads 0..127 (needs sXj)
    if (tid < 128) {
        int e = tid & 63;
        const float* xi = sXi[e >> 5];
        const float* xj = sXj[e];
        if (tid < 64) sPhi[e] = dihedral_f(&xi[6], &xj[0], &xj[3], &xj[6]);
        else          sPsi[e] = dihedral_f(&xi[0], &xi[3], &xi[6], &xj[0]);
    }

    // ---- A-matrix generator: geometric recurrence.
    const float Ac  = -0.92332482616893658f;
    const float K1c = 2.46219953645049755f;                 // -2*Ac*(4/3)
    const float Rc  = EXP2F(-1.64146635763366503f);         // 2^(Ac*(4/3)^2)
    const float R2c = Rc * Rc;
    int eg_ = w * 16 + (lane & 15);
    int q_ = lane >> 4;
    const float* xiG = sXi[eg_ >> 5];
    const float* xjG = sXj[eg_];
    short* rowp = sA + eg_ * SAW;
    float hfq = (float)(q_ & 1);              // o&1 == q&1 (o = q + 4t)

#define GEN_A(hh, CNT)                                                         \
    {                                                                          \
        _Pragma("unroll")                                                      \
        for (int t = 0; t < (CNT); t++) {                                      \
            int o = q_ + t * 4;                                                \
            int kg = (hh) * 224 + o * 8;                                       \
            int pair = kg >> 4;                                                \
            union { unsigned u[4]; v8s v; } au;                                \
            if (pair >= 25) {                                                  \
                if ((hh) == 1 && o == 22) {   /* kg==400: affine slots */      \
                    au.u[0] = bfpack(sEt[eg_], sPhi[eg_]);                     \
                    au.u[1] = bfpack(sPsi[eg_], 1.0f);                         \
                    au.u[2] = 0; au.u[3] = 0;                                  \
                } else {                                                       \
                    au.u[0] = 0; au.u[1] = 0; au.u[2] = 0; au.u[3] = 0;        \
                }                                                              \
            } else {                                                           \
                int a = pair / 5, cc = pair - a * 5;                           \
                float dx = xiG[a*3+0] - xjG[cc*3+0];                           \
                float dy = xiG[a*3+1] - xjG[cc*3+1];                           \
                float dz = xiG[a*3+2] - xjG[cc*3+2];                           \
                float d = sqrtf(dx*dx + dy*dy + dz*dz + 1e-6f);                \
                float ee = fminf(__fmaf_rn(hfq, -10.666666666666666f, d), 40.f); \
                float r0 = EXP2F(Ac * ee * ee);                                \
                float g  = EXP2F(K1c * ee) * Rc;                               \
                float r1 = r0 * g; g *= R2c;                                   \
                float r2 = r1 * g; g *= R2c;                                   \
                float r3 = r2 * g; g *= R2c;                                   \
                float r4 = r3 * g; g *= R2c;                                   \
                float r5 = r4 * g; g *= R2c;                                   \
                float r6 = r5 * g; g *= R2c;                                   \
                float r7 = r6 * g;                                             \
                au.u[0] = bfpack(r0, r1);                                      \
                au.u[1] = bfpack(r2, r3);                                      \
                au.u[2] = bfpack(r4, r5);                                      \
                au.u[3] = bfpack(r6, r7);                                      \
            }                                                                  \
            *(v8s*)(rowp + o * 8) = au.v;                                      \
        }                                                                      \
    }

    GEN_A(0, ACH)
    __syncthreads();

    // ---- MFMA: waves split N (2 nt tiles each); A from LDS, B from L2 (read once per block)
    int cl = lane & 15, kq = lane >> 4;
    int ntA = 2 * w, ntB = ntA + 1;
    const char* sAc = (const char*)sA;
    int abase0 = cl * (SAW * 2) + kq * 16;

    v4f acc[4][2];
#pragma unroll
    for (int eg = 0; eg < 4; eg++) { acc[eg][0] = (v4f){0.f,0.f,0.f,0.f}; acc[eg][1] = (v4f){0.f,0.f,0.f,0.f}; }

#define MMA_HALF(CHBASE, CNT)                                                  \
    {                                                                          \
        _Pragma("unroll 2")                                                    \
        for (int chl = 0; chl < (CNT); chl++) {                                \
            const v8s* gb = (const v8s*)WTf + ((size_t)((CHBASE) + chl) * 512 + lane); \
            v8s b0 = gb[ntA * 64];                                             \
            v8s b1 = gb[ntB * 64];                                             \
            int ab = abase0 + chl * 64;                                        \
            v8s a0 = *(const v8s*)(sAc + ab);                                  \
            v8s a1 = *(const v8s*)(sAc + ab + 16 * (SAW * 2));                 \
            v8s a2 = *(const v8s*)(sAc + ab + 32 * (SAW * 2));                 \
            v8s a3 = *(const v8s*)(sAc + ab + 48 * (SAW * 2));                 \
            acc[0][0] = __builtin_amdgcn_mfma_f32_16x16x32_bf16(a0, b0, acc[0][0], 0, 0, 0); \
            acc[0][1] = __builtin_amdgcn_mfma_f32_16x16x32_bf16(a0, b1, acc[0][1], 0, 0, 0); \
            acc[1][0] = __builtin_amdgcn_mfma_f32_16x16x32_bf16(a1, b0, acc[1][0], 0, 0, 0); \
            acc[1][1] = __builtin_amdgcn_mfma_f32_16x16x32_bf16(a1, b1, acc[1][1], 0, 0, 0); \
            acc[2][0] = __builtin_amdgcn_mfma_f32_16x16x32_bf16(a2, b0, acc[2][0], 0, 0, 0); \
            acc[2][1] = __builtin_amdgcn_mfma_f32_16x16x32_bf16(a2, b1, acc[2][1], 0, 0, 0); \
            acc[3][0] = __builtin_amdgcn_mfma_f32_16x16x32_bf16(a3, b0, acc[3][0], 0, 0, 0); \
            acc[3][1] = __builtin_amdgcn_mfma_f32_16x16x32_bf16(a3, b1, acc[3][1], 0, 0, 0); \
        }                                                                      \
    }

    MMA_HALF(0, ACH)
    __syncthreads();          // all waves done reading sA half A
    GEN_A(1, BCH)
    __syncthreads();
    MMA_HALF(ACH, BCH)

    // ---- epilogue: vals + cross-wave LN (sRed aliases dead sXj)
    float2* sRed = (float2*)&sXj[0][0];   // [64 edges][4 waves]
    int nA = ntA * 16 + cl, nB = nA + 16;
    float r4A = sRow[0][nA], r5A = sRow[1][nA];
    float r4B = sRow[0][nB], r5B = sRow[1][nB];

#pragma unroll
    for (int eg = 0; eg < 4; eg++) {
#pragma unroll
        for (int r = 0; r < 4; r++) {
            int e = eg * 16 + kq * 4 + r;
            int pos = sPos[e];
            float v0 = acc[eg][0][r] + We[pos * 128 + nA];
            float v1 = acc[eg][1][r] + We[pos * 128 + nB];
            acc[eg][0][r] = v0; acc[eg][1][r] = v1;
            float s = v0 + v1, q2 = v0 * v0 + v1 * v1;
#pragma unroll
            for (int s2 = 1; s2 < 16; s2 <<= 1) {
                s  += __shfl_xor(s,  s2, 64);
                q2 += __shfl_xor(q2, s2, 64);
            }
            if (cl == 0) sRed[e * 4 + w] = make_float2(s, q2);
        }
    }
    __syncthreads();

#pragma unroll
    for (int eg = 0; eg < 4; eg++) {
#pragma unroll
        for (int r = 0; r < 4; r++) {
            int e = eg * 16 + kq * 4 + r;
            float4 pa = *(const float4*)&sRed[e * 4];
            float4 pb = *(const float4*)&sRed[e * 4 + 2];
            float s  = pa.x + pa.z + pb.x + pb.z;
            float q2 = pa.y + pa.w + pb.y + pb.w;
            float mean = s * (1.0f / 128.0f);
            float var = q2 * (1.0f / 128.0f) - mean * mean;
            float rstd = rsqrtf(var + 1e-5f);
            size_t base = OFF_HE + (size_t)(e0 + e) * 128;
            out[base + nA] = (acc[eg][0][r] - mean) * rstd * r4A + r5A;
            out[base + nB] = (acc[eg][1][r] - mean) * rstd * r4B + r5B;
        }
    }
}

// ---------------- launch ----------------
extern "C" void kernel_launch(void* const* d_in, const int* in_sizes, int n_in,
                              void* d_out, int out_size, void* d_ws, size_t ws_size,
                              hipStream_t stream) {
    (void)in_sizes; (void)n_in; (void)out_size; (void)ws_size;
    const float* X    = (const float*)d_in[0];
    const int*   S    = (const int*)d_in[1];
    const float* BB   = (const float*)d_in[2];
    const float* SC   = (const float*)d_in[3];
    const int*   chain= (const int*)d_in[4];
    const float* mask = (const float*)d_in[5];
    const float* Wn   = (const float*)d_in[6];
    const float* bn   = (const float*)d_in[7];
    const float* gn   = (const float*)d_in[8];
    const float* betan= (const float*)d_in[9];
    const float* We   = (const float*)d_in[10];
    const float* be   = (const float*)d_in[11];
    const float* ge   = (const float*)d_in[12];
    const float* betae= (const float*)d_in[13];
    float* out = (float*)d_out;

    char* ws = (char*)d_ws;
    int*   EidxW = (int*)ws;                                  // 524288 B
    float* X5    = (float*)(ws + 524288);                     // 245760 B (ends 770048)
    short* WTf   = (short*)(ws + 770048);                     // 106496 B (ends 876544)

    hipLaunchKernelGGL(fused_pre_kernel, dim3(1024 + 16 + 26), dim3(256), 0, stream,
                       X, mask, S, BB, SC, Wn, bn, gn, betan, We, be,
                       X5, WTf, EidxW, out);
    hipLaunchKernelGGL(edge8_kernel, dim3(NB * NL * NK / 64), dim3(256), 0, stream,
                       X5, EidxW, chain, We, ge, betae, WTf, out);
}

// Round 8
// 154.120 us; speedup vs baseline: 1.3432x; 1.0357x over previous
//
#include <hip/hip_runtime.h>
#include <math.h>

#define NB 2
#define NL 2048
#define NK 32
#define NODE_F 128
#define EDGE_F 128

// output layout (float32 elements)
#define OFF_HV   0
#define OFF_HE   (NB*NL*NODE_F)                 // 524288
#define OFF_EIDX (OFF_HE + NB*NL*NK*EDGE_F)     // 17301504
#define OFF_X    (OFF_EIDX + NB*NL*NK)          // 17432576

#define ACH 7        // chunks (K=32) in half A
#define BCH 6        // chunks in half B
#define SAW 232      // sA row stride in shorts (464 B, 16B-aligned, bank-friendly)

typedef __attribute__((ext_vector_type(8))) short v8s;
typedef __attribute__((ext_vector_type(4))) float v4f;

__device__ __forceinline__ short f2bf(float f) {
    unsigned u = __float_as_uint(f);
    unsigned r = u + 0x7fffu + ((u >> 16) & 1u);
    return (short)(r >> 16);
}

#if __has_builtin(__builtin_amdgcn_exp2f)
#define EXP2F(x) __builtin_amdgcn_exp2f(x)
#else
#define EXP2F(x) __expf((x) * 0.6931471805599453f)
#endif

// pack top halves of two f32 bit-patterns (truncating f32->bf16) into one u32
__device__ __forceinline__ unsigned bfpack(float f0, float f1) {
    unsigned u0 = __float_as_uint(f0), u1 = __float_as_uint(f1);
#if __has_builtin(__builtin_amdgcn_perm)
    return __builtin_amdgcn_perm(u1, u0, 0x07060302u);  // {u1.hi16, u0.hi16}
#else
    return (u1 & 0xFFFF0000u) | (u0 >> 16);
#endif
}

// ---------------- DPP primitives (pure VALU, no LDS) ----------------
// row_shr:N with 0-fill: lane i reads lane i-N within its 16-lane row (invalid -> 0).
template<int CTRL>
__device__ __forceinline__ float dpp_add_f32(float x) {
    int p = __builtin_amdgcn_update_dpp(0, __float_as_int(x), CTRL, 0xF, 0xF, true);
    return x + __int_as_float(p);
}
template<int CTRL>
__device__ __forceinline__ float dpp_max_f32(float x) {
    int p = __builtin_amdgcn_update_dpp(0, __float_as_int(x), CTRL, 0xF, 0xF, true);
    return fmaxf(x, __int_as_float(p));
}
// 16-lane row sum: result in lane 15 of each row
__device__ __forceinline__ float dpp_row_sum16(float x) {
    x = dpp_add_f32<0x111>(x);   // row_shr:1
    x = dpp_add_f32<0x112>(x);   // row_shr:2
    x = dpp_add_f32<0x114>(x);   // row_shr:4
    x = dpp_add_f32<0x118>(x);   // row_shr:8
    return x;
}
// wave-wide sum: total lands in lane 63; broadcast via readlane
__device__ __forceinline__ float dpp_wave_sum(float x) {
    x = dpp_row_sum16(x);
    x = dpp_add_f32<0x142>(x);   // row_bcast15
    x = dpp_add_f32<0x143>(x);   // row_bcast31
    return __int_as_float(__builtin_amdgcn_readlane(__float_as_int(x), 63));
}
__device__ __forceinline__ float dpp_wave_max_nn(float x) {   // for x >= 0 (0-fill safe)
    x = dpp_max_f32<0x111>(x);
    x = dpp_max_f32<0x112>(x);
    x = dpp_max_f32<0x114>(x);
    x = dpp_max_f32<0x118>(x);
    x = dpp_max_f32<0x142>(x);
    x = dpp_max_f32<0x143>(x);
    return __int_as_float(__builtin_amdgcn_readlane(__float_as_int(x), 63));
}

// ---------------- DPP wave-min (u32) — lane 63 gets global min ----------------
template<int CTRL>
__device__ __forceinline__ unsigned dpp_min_u32_step(unsigned x) {
    unsigned p = (unsigned)__builtin_amdgcn_update_dpp((int)x, (int)x, CTRL, 0xF, 0xF, false);
    return p < x ? p : x;
}
__device__ __forceinline__ unsigned wave_min_u32_dpp(unsigned x) {
    x = dpp_min_u32_step<0xB1>(x);    // quad_perm [1,0,3,2]
    x = dpp_min_u32_step<0x4E>(x);    // quad_perm [2,3,0,1]
    x = dpp_min_u32_step<0x141>(x);   // row_half_mirror
    x = dpp_min_u32_step<0x140>(x);   // row_mirror
    x = dpp_min_u32_step<0x142>(x);   // row_bcast15
    x = dpp_min_u32_step<0x143>(x);   // row_bcast31
    return x;                         // lane 63 holds the global min
}

// ---------------- helpers ----------------
__device__ __forceinline__ void cross3(const float a[3], const float b[3], float c[3]) {
    c[0] = a[1]*b[2] - a[2]*b[1];
    c[1] = a[2]*b[0] - a[0]*b[2];
    c[2] = a[0]*b[1] - a[1]*b[0];
}
__device__ __forceinline__ float dot3(const float a[3], const float b[3]) {
    return a[0]*b[0] + a[1]*b[1] + a[2]*b[2];
}
__device__ float dihedral_f(const float p0[3], const float p1[3],
                            const float p2[3], const float p3[3]) {
    float u0[3], u1[3], u2[3];
    for (int d = 0; d < 3; d++) {
        u0[d] = p2[d] - p1[d];
        u1[d] = p0[d] - p1[d];
        u2[d] = p3[d] - p2[d];
    }
    float n1[3], n2[3], c12[3];
    cross3(u0, u1, n1);
    cross3(u0, u2, n2);
    cross3(u1, u2, c12);
    float l1 = sqrtf(dot3(n1, n1));
    float l2 = sqrtf(dot3(n2, n2));
    float cosang = dot3(n1, n2) / (l1 * l2);
    float s = dot3(c12, u0);
    float sgn = (s > 0.f) ? 1.f : ((s < 0.f) ? -1.f : 0.f);
    float r = sgn * acosf(cosang);
    return isnan(r) ? 0.f : r;
}

// ---------------- kernel 0: fused {knn_node blocks 0..1023}{prep 1024..1039}{wconv 1040..1065} ----------------
__global__ __launch_bounds__(256) void fused_pre_kernel(const float* __restrict__ X,
                                                        const float* __restrict__ mask,
                                                        const int* __restrict__ S,
                                                        const float* __restrict__ BB,
                                                        const float* __restrict__ SC,
                                                        const float* __restrict__ Wn,
                                                        const float* __restrict__ bn,
                                                        const float* __restrict__ gn,
                                                        const float* __restrict__ betan,
                                                        const float* __restrict__ We,
                                                        const float* __restrict__ be,
                                                        float* __restrict__ X5,
                                                        short* __restrict__ WTf,
                                                        int* __restrict__ EidxW,
                                                        float* __restrict__ out) {
    __shared__ float sCa[NL * 3];               // 24 KB : this block's batch Ca coords
    __shared__ unsigned long long sSel[4][64];  // 2 KB  : per-wave candidate slots
    int blk = blockIdx.x;
    int tid = threadIdx.x;

    if (blk >= 1024) {
        if (blk < 1040) {
            // ---- prep: X5 + X passthrough ----
            int row = (blk - 1024) * 256 + tid;
            float v[12];
#pragma unroll
            for (int t = 0; t < 12; t++) v[t] = X[row * 12 + t];
#pragma unroll
            for (int t = 0; t < 12; t++) out[OFF_X + row * 12 + t] = v[t];
            float bv[3], cv[3], cr[3];
            for (int d = 0; d < 3; d++) { bv[d] = v[3+d] - v[d]; cv[d] = v[6+d] - v[3+d]; }
            cross3(bv, cv, cr);
            float* x5 = X5 + row * 15;
#pragma unroll
            for (int t = 0; t < 12; t++) x5[t] = v[t];
            for (int d = 0; d < 3; d++)
                x5[12 + d] = -0.58273431f * cr[d] + 0.56802827f * bv[d] - 0.54067466f * cv[d] + v[3+d];
        } else {
            // ---- wconv: k<400 RBF rows We[65+k]; 400..402 = We[465..467]; 403 = be; else 0 ----
            int t = (blk - 1040) * 256 + tid;
            if (t >= 13 * 8 * 64) return;
            int lane = t & 63;
            int nt = (t >> 6) & 7;
            int ch = t >> 9;
            int n = nt * 16 + (lane & 15);
            int kbase = ch * 32 + (lane >> 4) * 8;
            short* dst = WTf + (size_t)t * 8;
#pragma unroll
            for (int j = 0; j < 8; j++) {
                int k = kbase + j;
                float f;
                if (k < 403) f = We[(65 + k) * 128 + n];
                else if (k == 403) f = be[n];
                else f = 0.f;
                dst[j] = f2bf(f);
            }
        }
        return;
    }

    // ---- knn + node: 4 rows per block ----
    int w = tid >> 6, l = tid & 63;
    int row = blk * 4 + w;
    int b = row / NL;
    int base = b * NL;

    // stage this batch's Ca into LDS (once per block)
    for (int idx = tid; idx < NL; idx += 256) {
        const float* xp = X + (size_t)(base + idx) * 12 + 3;
        sCa[idx * 3 + 0] = xp[0];
        sCa[idx * 3 + 1] = xp[1];
        sCa[idx * 3 + 2] = xp[2];
    }

    // node features + LN (hides staging latency; independent of sCa)
    {
        int f0 = l, f1 = 64 + l;
        int s = S[row];
        float a0 = bn[f0] + Wn[s * NODE_F + f0];
        float a1 = bn[f1] + Wn[s * NODE_F + f1];
#pragma unroll
        for (int t = 0; t < 6; t++) {
            float x = BB[row * 6 + t];
            a0 += x * Wn[(21 + t) * NODE_F + f0];
            a1 += x * Wn[(21 + t) * NODE_F + f1];
        }
#pragma unroll
        for (int t = 0; t < 8; t++) {
            float x = SC[row * 8 + t];
            a0 += x * Wn[(27 + t) * NODE_F + f0];
            a1 += x * Wn[(27 + t) * NODE_F + f1];
        }
        float tot = dpp_wave_sum(a0 + a1);
        float mean = tot * (1.0f / 128.0f);
        float d0 = a0 - mean, d1 = a1 - mean;
        float qt = dpp_wave_sum(d0 * d0 + d1 * d1);
        float rstd = 1.0f / sqrtf(qt * (1.0f / 128.0f) + 1e-5f);
        out[OFF_HV + row * NODE_F + f0] = d0 * rstd * gn[f0] + betan[f0];
        out[OFF_HV + row * NODE_F + f1] = d1 * rstd * gn[f1] + betan[f1];
    }
    __syncthreads();

    const float* mrow = mask + base;
    int lrow = row - base;
    float cx = sCa[lrow * 3 + 0], cy = sCa[lrow * 3 + 1], cz = sCa[lrow * 3 + 2];
    float mi = mrow[lrow];

    // ---- adjusted distances (bit-identical selection semantics) ----
    float K[32];
    float lmax = 0.0f;
#pragma unroll
    for (int t = 0; t < 32; t++) {
        int j = t * 64 + l;
        float dx = __fsub_rn(cx, sCa[j * 3 + 0]);
        float dy = __fsub_rn(cy, sCa[j * 3 + 1]);
        float dz = __fsub_rn(cz, sCa[j * 3 + 2]);
        float ss = __fadd_rn(__fadd_rn(__fadd_rn(__fmul_rn(dx, dx), __fmul_rn(dy, dy)),
                                       __fmul_rn(dz, dz)), 1e-6f);
        float d = __fmul_rn(__fmul_rn(mi, mrow[j]), __fsqrt_rn(ss));
        K[t] = d;
        lmax = fmaxf(lmax, d);
    }
    lmax = dpp_wave_max_nn(lmax);
#pragma unroll
    for (int t = 0; t < 32; t++) {
        int j = t * 64 + l;
        float m2 = __fmul_rn(mi, mrow[j]);
        K[t] = __fadd_rn(K[t], __fmul_rn(__fmul_rn(2.0f, __fsub_rn(1.0f, m2)), lmax));
    }

    // ---- radix binary-search for tau: count(K <= tau) in [32, 64] ----
    unsigned lo_ = 0u, hi_ = 0x7f7fffffu, tau = 0x7f7fffffu;
#pragma unroll 1
    for (int it = 0; it < 31; it++) {
        unsigned mid = (lo_ + hi_) >> 1;
        float tf = __uint_as_float(mid);
        int c = 0;
#pragma unroll
        for (int t = 0; t < 32; t++) c += __popcll(__ballot(K[t] <= tf));
        if (c >= 32) {
            tau = mid;
            if (c <= 64) break;
            hi_ = mid - 1;
        } else {
            lo_ = mid + 1;
        }
    }
    float tauf = __uint_as_float(tau);

    // ---- compact candidates into slots (slot order == ascending j -> exact tie semantics) ----
    sSel[w][l] = ~0ull;
    int cbase = 0;
#pragma unroll
    for (int t = 0; t < 32; t++) {
        bool q = (K[t] <= tauf);
        unsigned long long m = __ballot(q);
        int pos = cbase + __popcll(m & ((1ull << l) - 1ull));
        if (q && pos < 64)
            sSel[w][pos] = (((unsigned long long)__float_as_uint(K[t])) << 32)
                           | (unsigned)(t * 64 + l);
        cbase += __popcll(m);
    }

    // ---- 32 extract-min rounds over 64 candidates (1 key/lane) ----
    unsigned long long key = sSel[w][l];
    int selj = 0;
#pragma unroll 1
    for (int r = 0; r < NK; r++) {
        unsigned hi = (unsigned)(key >> 32);
        unsigned gh = (unsigned)__builtin_amdgcn_readlane((int)wave_min_u32_dpp(hi), 63);
        unsigned long long mask_ = __ballot(hi == gh);
        int wl = __ffsll((unsigned long long)mask_) - 1;   // first lane == smallest slot == smallest j
        unsigned j = (unsigned)__builtin_amdgcn_readlane((int)(unsigned)key, wl);
        if (l == r) selj = (int)j;
        if (l == wl) key = ~0ull;
    }
    if (l < NK) {
        EidxW[row * NK + l] = selj;
        out[OFF_EIDX + row * NK + l] = (float)selj;
    }
}

// ---------------- kernel 1: edge9 — A in LDS, DPP epilogue reductions (no ds_bpermute) ----------------
__global__ __launch_bounds__(256, 4) void edge9_kernel(const float* __restrict__ X5,
                                                       const int* __restrict__ Eidx,
                                                       const int* __restrict__ chain,
                                                       const float* __restrict__ We,
                                                       const float* __restrict__ ge,
                                                       const float* __restrict__ betae,
                                                       const short* __restrict__ WTf,
                                                       float* __restrict__ out) {
    __shared__ short sA[64 * SAW];        // 29696 B : bf16 A-matrix, one K-half at a time
    __shared__ float sXj[64][17];         // 4352 B  : aliased by sRed in the epilogue
    __shared__ float sXi[2][15];          // 120 B
    __shared__ float sRow[2][128];        // 1024 B : ge, betae
    __shared__ int   sJ[64];              // 256 B
    __shared__ int   sPos[64];            // 256 B
    __shared__ float sEt[64], sPhi[64], sPsi[64];   // 768 B

    int tid = threadIdx.x;
    int e0 = blockIdx.x * 64;
    int b = e0 / (NL * NK);
    int i0 = (e0 / NK) % NL;
    int lane = tid & 63, w = tid >> 6;

    // ---- phase 0a: indices + small tables
    if (tid < 64) sJ[tid] = Eidx[e0 + tid];
    if (tid < 30) sXi[tid / 15][tid % 15] = X5[(b * NL + i0 + tid / 15) * 15 + (tid % 15)];
    if (tid >= 128 && tid < 128 + 128) {
        int n2 = tid - 128;
        sRow[0][n2] = ge[n2];
        sRow[1][n2] = betae[n2];
    }
    __syncthreads();

    // ---- phase 0b: gather neighbor coords, pos/type
    for (int t = tid; t < 64 * 15; t += 256) {
        int e = t / 15, c2 = t % 15;
        sXj[e][c2] = X5[(b * NL + sJ[e]) * 15 + c2];
    }
    if (tid < 64) {
        int e = tid;
        int i = i0 + (e >> 5);
        int j = sJ[e];
        int off = j - i + 32;
        off = off < 0 ? 0 : (off > 64 ? 64 : off);
        sPos[e] = off;
        sEt[e] = (chain[b * NL + j] == chain[b * NL + i]) ? 2.0f : 1.0f;
    }
    __syncthreads();

    // ---- phase 0c: dihedrals on threads 0..127 (needs sXj)
    if (tid < 128) {
        int e = tid & 63;
        const float* xi = sXi[e >> 5];
        const float* xj = sXj[e];
        if (tid < 64) sPhi[e] = dihedral_f(&xi[6], &xj[0], &xj[3], &xj[6]);
        else          sPsi[e] = dihedral_f(&xi[0], &xi[3], &xi[6], &xj[0]);
    }

    // ---- A-matrix generator: geometric recurrence (2 exp/octet).
    const float Ac  = -0.92332482616893658f;
    const float K1c = 2.46219953645049755f;                 // -2*Ac*(4/3)
    const float Rc  = EXP2F(-1.64146635763366503f);         // 2^(Ac*(4/3)^2)
    const float R2c = Rc * Rc;
    int eg_ = w * 16 + (lane & 15);
    int q_ = lane >> 4;
    const float* xiG = sXi[eg_ >> 5];
    const float* xjG = sXj[eg_];
    short* rowp = sA + eg_ * SAW;
    float hfq = (float)(q_ & 1);              // o&1 == q&1 (o = q + 4t)

#define GEN_A(hh, CNT)                                                         \
    {                                                                          \
        _Pragma("unroll")                                                      \
        for (int t = 0; t < (CNT); t++) {                                      \
            int o = q_ + t * 4;                                                \
            int kg = (hh) * 224 + o * 8;                                       \
            int pair = kg >> 4;                                                \
            union { unsigned u[4]; v8s v; } au;                                \
            if (pair >= 25) {                                                  \
                if ((hh) == 1 && o == 22) {   /* kg==400: affine slots */      \
                    au.u[0] = bfpack(sEt[eg_], sPhi[eg_]);                     \
                    au.u[1] = bfpack(sPsi[eg_], 1.0f);                         \
                    au.u[2] = 0; au.u[3] = 0;                                  \
                } else {                                                       \
                    au.u[0] = 0; au.u[1] = 0; au.u[2] = 0; au.u[3] = 0;        \
                }                                                              \
            } else {                                                           \
                int a = pair / 5, cc = pair - a * 5;                           \
                float dx = xiG[a*3+0] - xjG[cc*3+0];                           \
                float dy = xiG[a*3+1] - xjG[cc*3+1];                           \
                float dz = xiG[a*3+2] - xjG[cc*3+2];                           \
                float d = sqrtf(dx*dx + dy*dy + dz*dz + 1e-6f);                \
                float ee = fminf(__fmaf_rn(hfq, -10.666666666666666f, d), 40.f); \
                float r0 = EXP2F(Ac * ee * ee);                                \
                float g  = EXP2F(K1c * ee) * Rc;                               \
                float r1 = r0 * g; g *= R2c;                                   \
                float r2 = r1 * g; g *= R2c;                                   \
                float r3 = r2 * g; g *= R2c;                                   \
                float r4 = r3 * g; g *= R2c;                                   \
                float r5 = r4 * g; g *= R2c;                                   \
                float r6 = r5 * g; g *= R2c;                                   \
                float r7 = r6 * g;                                             \
                au.u[0] = bfpack(r0, r1);                                      \
                au.u[1] = bfpack(r2, r3);                                      \
                au.u[2] = bfpack(r4, r5);                                      \
                au.u[3] = bfpack(r6, r7);                                      \
            }                                                                  \
            *(v8s*)(rowp + o * 8) = au.v;                                      \
        }                                                                      \
    }

    GEN_A(0, ACH)
    __syncthreads();

    // ---- MFMA: waves split N (2 nt tiles each); A from LDS, B from L2 (read once per block)
    int cl = lane & 15, kq = lane >> 4;
    int ntA = 2 * w, ntB = ntA + 1;
    const char* sAc = (const char*)sA;
    int abase0 = cl * (SAW * 2) + kq * 16;

    v4f acc[4][2];
#pragma unroll
    for (int eg = 0; eg < 4; eg++) { acc[eg][0] = (v4f){0.f,0.f,0.f,0.f}; acc[eg][1] = (v4f){0.f,0.f,0.f,0.f}; }

#define MMA_HALF(CHBASE, CNT)                                                  \
    {                                                                          \
        _Pragma("unroll 2")                                                    \
        for (int chl = 0; chl < (CNT); chl++) {                                \
            const v8s* gb = (const v8s*)WTf + ((size_t)((CHBASE) + chl) * 512 + lane); \
            v8s b0 = gb[ntA * 64];                                             \
            v8s b1 = gb[ntB * 64];                                             \
            int ab = abase0 + chl * 64;                                        \
            v8s a0 = *(const v8s*)(sAc + ab);                                  \
            v8s a1 = *(const v8s*)(sAc + ab + 16 * (SAW * 2));                 \
            v8s a2 = *(const v8s*)(sAc + ab + 32 * (SAW * 2));                 \
            v8s a3 = *(const v8s*)(sAc + ab + 48 * (SAW * 2));                 \
            acc[0][0] = __builtin_amdgcn_mfma_f32_16x16x32_bf16(a0, b0, acc[0][0], 0, 0, 0); \
            acc[0][1] = __builtin_amdgcn_mfma_f32_16x16x32_bf16(a0, b1, acc[0][1], 0, 0, 0); \
            acc[1][0] = __builtin_amdgcn_mfma_f32_16x16x32_bf16(a1, b0, acc[1][0], 0, 0, 0); \
            acc[1][1] = __builtin_amdgcn_mfma_f32_16x16x32_bf16(a1, b1, acc[1][1], 0, 0, 0); \
            acc[2][0] = __builtin_amdgcn_mfma_f32_16x16x32_bf16(a2, b0, acc[2][0], 0, 0, 0); \
            acc[2][1] = __builtin_amdgcn_mfma_f32_16x16x32_bf16(a2, b1, acc[2][1], 0, 0, 0); \
            acc[3][0] = __builtin_amdgcn_mfma_f32_16x16x32_bf16(a3, b0, acc[3][0], 0, 0, 0); \
            acc[3][1] = __builtin_amdgcn_mfma_f32_16x16x32_bf16(a3, b1, acc[3][1], 0, 0, 0); \
        }                                                                      \
    }

    MMA_HALF(0, ACH)
    __syncthreads();          // all waves done reading sA half A
    GEN_A(1, BCH)
    __syncthreads();
    MMA_HALF(ACH, BCH)

    // ---- epilogue: vals + cross-wave LN (sRed aliases dead sXj); DPP row sums, no ds_bpermute
    float2* sRed = (float2*)&sXj[0][0];   // [64 edges][4 waves]
    int nA = ntA * 16 + cl, nB = nA + 16;
    float r4A = sRow[0][nA], r5A = sRow[1][nA];
    float r4B = sRow[0][nB], r5B = sRow[1][nB];

#pragma unroll
    for (int eg = 0; eg < 4; eg++) {
#pragma unroll
        for (int r = 0; r < 4; r++) {
            int e = eg * 16 + kq * 4 + r;
            int pos = sPos[e];
            float v0 = acc[eg][0][r] + We[pos * 128 + nA];
            float v1 = acc[eg][1][r] + We[pos * 128 + nB];
            acc[eg][0][r] = v0; acc[eg][1][r] = v1;
            float s  = dpp_row_sum16(v0 + v1);
            float q2 = dpp_row_sum16(v0 * v0 + v1 * v1);
            if (cl == 15) sRed[e * 4 + w] = make_float2(s, q2);
        }
    }
    __syncthreads();

#pragma unroll
    for (int eg = 0; eg < 4; eg++) {
#pragma unroll
        for (int r = 0; r < 4; r++) {
            int e = eg * 16 + kq * 4 + r;
            float4 pa = *(const float4*)&sRed[e * 4];
            float4 pb = *(const float4*)&sRed[e * 4 + 2];
            float s  = pa.x + pa.z + pb.x + pb.z;
            float q2 = pa.y + pa.w + pb.y + pb.w;
            float mean = s * (1.0f / 128.0f);
            float var = q2 * (1.0f / 128.0f) - mean * mean;
            float rstd = rsqrtf(var + 1e-5f);
            size_t base = OFF_HE + (size_t)(e0 + e) * 128;
            out[base + nA] = (acc[eg][0][r] - mean) * rstd * r4A + r5A;
            out[base + nB] = (acc[eg][1][r] - mean) * rstd * r4B + r5B;
        }
    }
}

// ---------------- launch ----------------
extern "C" void kernel_launch(void* const* d_in, const int* in_sizes, int n_in,
                              void* d_out, int out_size, void* d_ws, size_t ws_size,
                              hipStream_t stream) {
    (void)in_sizes; (void)n_in; (void)out_size; (void)ws_size;
    const float* X    = (const float*)d_in[0];
    const int*   S    = (const int*)d_in[1];
    const float* BB   = (const float*)d_in[2];
    const float* SC   = (const float*)d_in[3];
    const int*   chain= (const int*)d_in[4];
    const float* mask = (const float*)d_in[5];
    const float* Wn   = (const float*)d_in[6];
    const float* bn   = (const float*)d_in[7];
    const float* gn   = (const float*)d_in[8];
    const float* betan= (const float*)d_in[9];
    const float* We   = (const float*)d_in[10];
    const float* be   = (const float*)d_in[11];
    const float* ge   = (const float*)d_in[12];
    const float* betae= (const float*)d_in[13];
    float* out = (float*)d_out;

    char* ws = (char*)d_ws;
    int*   EidxW = (int*)ws;                                  // 524288 B
    float* X5    = (float*)(ws + 524288);                     // 245760 B (ends 770048)
    short* WTf   = (short*)(ws + 770048);                     // 106496 B (ends 876544)

    hipLaunchKernelGGL(fused_pre_kernel, dim3(1024 + 16 + 26), dim3(256), 0, stream,
                       X, mask, S, BB, SC, Wn, bn, gn, betan, We, be,
                       X5, WTf, EidxW, out);
    hipLaunchKernelGGL(edge9_kernel, dim3(NB * NL * NK / 64), dim3(256), 0, stream,
                       X5, EidxW, chain, We, ge, betae, WTf, out);
}